// Round 7
// baseline (20018.445 us; speedup 1.0000x reference)
//
#include <hip/hip_runtime.h>
#include <stdint.h>

#define B_ 32
#define T_ 2048
#define H_ 256
#define M_ 64
#define L_ 256
#define G4_ 1024     // 4*H gate rows

#define NG_ 8        // batch groups (4 batches each); grp = bid&7 -> same XCD under round-robin
#define NSL_ 16      // hidden slices per group
#define EPT_ 16      // h elements per slice
#define RING_ 8      // ring slots; block skew <=1 so reuse distance 8 is safe

__device__ __forceinline__ float sig_fast(float x){ return 1.f/(1.f+__expf(-x)); }
__device__ __forceinline__ float tanh_fast(float x){ return 2.f/(1.f+__expf(-2.f*x)) - 1.f; }
__device__ __forceinline__ float dot4(float4 a, float4 b){
  return fmaf(a.x,b.x, fmaf(a.y,b.y, fmaf(a.z,b.z, a.w*b.w)));
}

// sc0 = gfx950 GLC: L1-bypass, coherent at the XCD's L2. Valid ONLY when
// producer and consumer share an XCD (runtime-detected below).
__device__ __forceinline__ unsigned long long ld_sc0_u64(const unsigned long long* p){
  unsigned long long r;
  asm volatile("global_load_dwordx2 %0, %1, off sc0\n\ts_waitcnt vmcnt(0)"
               : "=v"(r) : "v"(p) : "memory");
  return r;
}
__device__ __forceinline__ void st_sc0_u64(unsigned long long* p, unsigned long long v){
  asm volatile("global_store_dwordx2 %0, %1, off sc0" :: "v"(p), "v"(v) : "memory");
}
__device__ __forceinline__ unsigned long long ld_agent_u64(const unsigned long long* p){
  return __hip_atomic_load(p, __ATOMIC_RELAXED, __HIP_MEMORY_SCOPE_AGENT);
}

// ---------------- prep kernels ----------------
__global__ void prep_wdc(const float* __restrict__ a, const float* __restrict__ b,
                         float* __restrict__ o){
  int i = blockIdx.x*256 + threadIdx.x;
  o[i] = a[i] + b[i];
}

__global__ void prep_small(const float* __restrict__ Wp, const float* __restrict__ bp,
                           const float* __restrict__ Wihe, const float* __restrict__ bihe,
                           const float* __restrict__ bhhe, const float* __restrict__ bihd,
                           const float* __restrict__ bhhd, const float* __restrict__ Wq,
                           float* __restrict__ Wc0, float* __restrict__ Wc1,
                           float* __restrict__ bc, float* __restrict__ bdc,
                           float* __restrict__ WqT){
  int idx = blockIdx.x*256 + threadIdx.x;
  if (idx < 16384){                 // WqT[m][k] = Wq[k][m]
    int m = idx >> 8, k = idx & 255;
    WqT[m*256 + k] = Wq[k*64 + m];
  } else if (idx < 16384 + 1024){   // fused input coeffs per gate row
    int j = idx - 16384;
    const float* wr = Wihe + j*256;
    float a0=0.f, a1=0.f, ab=0.f;
    for (int e=0;e<256;e++){
      float w = wr[e];
      a0 = fmaf(Wp[e],     w, a0);
      a1 = fmaf(Wp[256+e], w, a1);
      ab = fmaf(bp[e],     w, ab);
    }
    Wc0[j] = a0; Wc1[j] = a1;
    bc[j]  = ab + bihe[j] + bhhe[j];
    bdc[j] = bihd[j] + bhhd[j];
  }
}

// ---------------- encoder LSTM body (FAST = same-XCD sc0 exchange) ----------------
template<bool FAST>
__device__ __forceinline__ void enc_body(
    const float* __restrict__ seq,
    float4 w0, float4 w1, float4 w2, float4 w3,
    float c0, float c1, float cbv,
    float* __restrict__ h_all, float* __restrict__ cT,
    unsigned long long* __restrict__ ringg,
    int grp, int slice, int tid, int myb, int mylen)
{
  __shared__ float hbuf[4][256];
  __shared__ float sbuf[4][2];
  __shared__ float gbuf[4][64];

  const int rp = tid >> 4, kc = tid & 15;
  const int ub = tid >> 4, ue = tid & 15;   // updater mapping (tid<64)
  float creg = 0.f;

  const int ib = tid >> 8, ik = tid & 255;  // consumer mapping: batch, elem
  const bool poller = ((ik >> 4) != slice); // own slice arrives via LDS short-circuit

  for (int t = 0; t < T_; ++t){
    if (tid < 8) sbuf[tid>>1][tid&1] = seq[((size_t)(grp + 8*(tid>>1))*T_ + t)*2 + (tid&1)];

    if (t == 0){
      hbuf[ib][ik] = 0.f;
    } else if (poller){
      const unsigned long long* pp = ringg + (size_t)((t-1) & (RING_-1))*1024 + tid;
      const unsigned tg = (unsigned)t;
      unsigned long long v; unsigned r = 0;
      do {
        if (FAST && ((++r) & 63u)) v = ld_sc0_u64(pp);   // L2-local fast poll
        else                       v = ld_agent_u64(pp); // hang-proof fallback
      } while ((unsigned)(v >> 32) != tg);
      hbuf[ib][ik] = __uint_as_float((unsigned)v);
    }
    __syncthreads();  // B1: hbuf/sbuf ready

#pragma unroll
    for (int i = 0; i < 4; ++i){
      float4 h0 = *(const float4*)&hbuf[i][       kc*4];
      float4 h1 = *(const float4*)&hbuf[i][ 64 + kc*4];
      float4 h2 = *(const float4*)&hbuf[i][128 + kc*4];
      float4 h3 = *(const float4*)&hbuf[i][192 + kc*4];
      float a = dot4(w0,h0) + dot4(w1,h1) + dot4(w2,h2) + dot4(w3,h3);
#pragma unroll
      for (int off = 1; off < 16; off <<= 1) a += __shfl_xor(a, off);
      if (kc == 0)
        gbuf[i][rp] = fmaf(sbuf[i][0], c0, fmaf(sbuf[i][1], c1, a + cbv));
    }
    __syncthreads();  // B2: gbuf ready

    if (tid < 64){
      float gi = gbuf[ub][      ue];
      float gf = gbuf[ub][16 + ue];
      float gg = gbuf[ub][32 + ue];
      float go = gbuf[ub][48 + ue];
      creg = sig_fast(gf)*creg + sig_fast(gi)*tanh_fast(gg);
      float h = sig_fast(go)*tanh_fast(creg);
      unsigned long long pk = ((unsigned long long)(unsigned)(t+1) << 32)
                            | (unsigned long long)__float_as_uint(h);
      unsigned long long* dst = ringg + (size_t)(t & (RING_-1))*1024 + ub*256 + slice*EPT_ + ue;
      if (FAST) st_sc0_u64(dst, pk);
      else __hip_atomic_store(dst, pk, __ATOMIC_RELAXED, __HIP_MEMORY_SCOPE_AGENT);
      hbuf[ub][slice*EPT_ + ue] = h;                            // own-slice short-circuit
      h_all[((size_t)t*B_ + myb)*H_ + slice*EPT_ + ue] = h;     // off critical path
      if (t == mylen - 1) cT[myb*H_ + slice*EPT_ + ue] = creg;
    }
    // next-iter staging writes only remote hbuf regions; compute waits at B1
  }
}

__global__ __launch_bounds__(1024) void enc_kernel(
    const float* __restrict__ seq, const int* __restrict__ slen,
    const float* __restrict__ Whh,
    const float* __restrict__ Wc0, const float* __restrict__ Wc1,
    const float* __restrict__ bc,
    float* __restrict__ h_all, float* __restrict__ cT,
    unsigned long long* __restrict__ ring, int* __restrict__ xb)
{
  const int tid = threadIdx.x;
  const int grp = blockIdx.x & 7, slice = blockIdx.x >> 3;
  const int rp = tid >> 4, kc = tid & 15;
  const int j = ((rp >> 4) << 8) + slice*EPT_ + (rp & 15);
  float4 w0 = *(const float4*)(Whh + (size_t)j*256 +   0 + kc*4);
  float4 w1 = *(const float4*)(Whh + (size_t)j*256 +  64 + kc*4);
  float4 w2 = *(const float4*)(Whh + (size_t)j*256 + 128 + kc*4);
  float4 w3 = *(const float4*)(Whh + (size_t)j*256 + 192 + kc*4);
  float c0 = Wc0[j], c1 = Wc1[j], cbv = bc[j];
  int myb = 0, mylen = -1;
  if (tid < 64){ myb = grp + 8*(tid>>4); mylen = slen[myb]; }
  unsigned long long* ringg = ring + (size_t)grp * (RING_*1024);

  // ---- per-group XCD-uniformity detection (agent-scope, one-time) ----
  int myxcd;
  asm("s_getreg_b32 %0, hwreg(HW_REG_XCC_ID)" : "=s"(myxcd));
  __shared__ int sfast;
  if (tid == 0){
    sfast = 1;
    __hip_atomic_store(xb + grp*NSL_ + slice, myxcd + 1,
                       __ATOMIC_RELAXED, __HIP_MEMORY_SCOPE_AGENT);
  }
  __syncthreads();
  if (tid < NSL_){
    int v;
    do { v = __hip_atomic_load(xb + grp*NSL_ + tid,
                               __ATOMIC_RELAXED, __HIP_MEMORY_SCOPE_AGENT); } while (v == 0);
    if (v != myxcd + 1) sfast = 0;
  }
  __syncthreads();

  if (sfast) enc_body<true >(seq, w0,w1,w2,w3, c0,c1,cbv, h_all, cT, ringg, grp, slice, tid, myb, mylen);
  else       enc_body<false>(seq, w0,w1,w2,w3, c0,c1,cbv, h_all, cT, ringg, grp, slice, tid, myb, mylen);
}

// ---------------- decoder LSTM body ----------------
template<bool FAST>
__device__ __forceinline__ void dec_body(
    float4 w0, float4 w1, float4 w2, float4 w3, float cbv,
    const float* __restrict__ h_all, float* __restrict__ h2_all,
    unsigned long long* __restrict__ ringg,
    int grp, int slice, int tid, int myb, float creg0, int stage_len)
{
  __shared__ float hbuf[4][256];
  __shared__ float gbuf[4][64];

  const int rp = tid >> 4, kc = tid & 15;
  const int ub = tid >> 4, ue = tid & 15;
  float creg = creg0;

  const int tb = tid >> 7, kp = tid & 127;  // s==0 bulk-stage mapping (tid<512)
  const int stage_b = grp + 8*tb;
  const int ib = tid >> 8, ik = tid & 255;
  const bool poller = ((ik >> 4) != slice);

  for (int s = 0; s < L_; ++s){
    if (s == 0){
      if (tid < 512)   // h_all fully written by completed enc kernel: plain loads OK
        *(float2*)&hbuf[tb][kp*2] =
            *(const float2*)(h_all + ((size_t)(stage_len-1)*B_ + stage_b)*H_ + kp*2);
    } else if (poller){
      const unsigned long long* pp = ringg + (size_t)((s-1) & (RING_-1))*1024 + tid;
      const unsigned tg = (unsigned)s;
      unsigned long long v; unsigned r = 0;
      do {
        if (FAST && ((++r) & 63u)) v = ld_sc0_u64(pp);
        else                       v = ld_agent_u64(pp);
      } while ((unsigned)(v >> 32) != tg);
      hbuf[ib][ik] = __uint_as_float((unsigned)v);
    }
    __syncthreads();  // B1

#pragma unroll
    for (int i = 0; i < 4; ++i){
      float4 h0 = *(const float4*)&hbuf[i][       kc*4];
      float4 h1 = *(const float4*)&hbuf[i][ 64 + kc*4];
      float4 h2 = *(const float4*)&hbuf[i][128 + kc*4];
      float4 h3 = *(const float4*)&hbuf[i][192 + kc*4];
      float a = dot4(w0,h0) + dot4(w1,h1) + dot4(w2,h2) + dot4(w3,h3);
#pragma unroll
      for (int off = 1; off < 16; off <<= 1) a += __shfl_xor(a, off);
      if (kc == 0) gbuf[i][rp] = a + cbv;
    }
    __syncthreads();  // B2

    if (tid < 64){
      float gi = gbuf[ub][      ue];
      float gf = gbuf[ub][16 + ue];
      float gg = gbuf[ub][32 + ue];
      float go = gbuf[ub][48 + ue];
      creg = sig_fast(gf)*creg + sig_fast(gi)*tanh_fast(gg);
      float h = sig_fast(go)*tanh_fast(creg);
      unsigned long long pk = ((unsigned long long)(unsigned)(s+1) << 32)
                            | (unsigned long long)__float_as_uint(h);
      unsigned long long* dst = ringg + (size_t)(s & (RING_-1))*1024 + ub*256 + slice*EPT_ + ue;
      if (FAST) st_sc0_u64(dst, pk);
      else __hip_atomic_store(dst, pk, __ATOMIC_RELAXED, __HIP_MEMORY_SCOPE_AGENT);
      hbuf[ub][slice*EPT_ + ue] = h;
      h2_all[((size_t)s*B_ + myb)*H_ + slice*EPT_ + ue] = h;
    }
  }
}

__global__ __launch_bounds__(1024) void dec_kernel(
    const int* __restrict__ slen,
    const float* __restrict__ Wdc, const float* __restrict__ bdc,
    const float* __restrict__ h_all, const float* __restrict__ cT,
    float* __restrict__ h2_all,
    unsigned long long* __restrict__ ring, int* __restrict__ xb)
{
  const int tid = threadIdx.x;
  const int grp = blockIdx.x & 7, slice = blockIdx.x >> 3;
  const int rp = tid >> 4, kc = tid & 15;
  const int j = ((rp >> 4) << 8) + slice*EPT_ + (rp & 15);
  float4 w0 = *(const float4*)(Wdc + (size_t)j*256 +   0 + kc*4);
  float4 w1 = *(const float4*)(Wdc + (size_t)j*256 +  64 + kc*4);
  float4 w2 = *(const float4*)(Wdc + (size_t)j*256 + 128 + kc*4);
  float4 w3 = *(const float4*)(Wdc + (size_t)j*256 + 192 + kc*4);
  float cbv = bdc[j];
  int myb = 0; float creg0 = 0.f;
  if (tid < 64){ myb = grp + 8*(tid>>4); creg0 = cT[myb*H_ + slice*EPT_ + (tid&15)]; }
  int stage_len = 1;
  if (tid < 512) stage_len = slen[grp + 8*(tid>>7)];
  unsigned long long* ringg = ring + (size_t)grp * (RING_*1024);

  int myxcd;
  asm("s_getreg_b32 %0, hwreg(HW_REG_XCC_ID)" : "=s"(myxcd));
  __shared__ int sfast;
  if (tid == 0){
    sfast = 1;
    __hip_atomic_store(xb + grp*NSL_ + slice, myxcd + 1,
                       __ATOMIC_RELAXED, __HIP_MEMORY_SCOPE_AGENT);
  }
  __syncthreads();
  if (tid < NSL_){
    int v;
    do { v = __hip_atomic_load(xb + grp*NSL_ + tid,
                               __ATOMIC_RELAXED, __HIP_MEMORY_SCOPE_AGENT); } while (v == 0);
    if (v != myxcd + 1) sfast = 0;
  }
  __syncthreads();

  if (sfast) dec_body<true >(w0,w1,w2,w3, cbv, h_all, h2_all, ringg, grp, slice, tid, myb, creg0, stage_len);
  else       dec_body<false>(w0,w1,w2,w3, cbv, h_all, h2_all, ringg, grp, slice, tid, myb, creg0, stage_len);
}

// ---------------- kproj = masked(enc) @ Wk + bk ----------------
__global__ __launch_bounds__(256) void kproj_kernel(
    const float* __restrict__ h_all, const int* __restrict__ slen,
    const float* __restrict__ Wk, const float* __restrict__ bk,
    float* __restrict__ kp)
{
  __shared__ float wk[256*64];
  const int tid = threadIdx.x;
  const int b = blockIdx.x >> 4, tc = blockIdx.x & 15;
  const int t0 = tc*128;
#pragma unroll
  for (int i=0;i<16;i++){
    int idx = tid + i*256;
    *(float4*)(&wk[idx*4]) = *(const float4*)(Wk + idx*4);
  }
  __syncthreads();
  const int tp = tid>>2, mc = (tid&3)*16;
  const int ta = t0 + tp*2, tb = ta+1;
  const int len = slen[b];
  const bool va = ta < len, vb = tb < len;
  const float* ha = h_all + ((size_t)ta*B_ + b)*H_;
  const float* hb = h_all + ((size_t)tb*B_ + b)*H_;
  float4 A[4], Bv[4];
#pragma unroll
  for (int u=0;u<4;u++){ A[u].x=A[u].y=A[u].z=A[u].w=0.f; Bv[u]=A[u]; }

  for (int k4=0;k4<64;k4++){
    float xa[4], xb_[4];
    if (va){ float4 v = *(const float4*)(ha + k4*4); xa[0]=v.x; xa[1]=v.y; xa[2]=v.z; xa[3]=v.w; }
    else   { xa[0]=xa[1]=xa[2]=xa[3]=0.f; }
    if (vb){ float4 v = *(const float4*)(hb + k4*4); xb_[0]=v.x; xb_[1]=v.y; xb_[2]=v.z; xb_[3]=v.w; }
    else   { xb_[0]=xb_[1]=xb_[2]=xb_[3]=0.f; }
#pragma unroll
    for (int jj=0;jj<4;jj++){
      const float* wr = &wk[(k4*4+jj)*64 + mc];
#pragma unroll
      for (int u=0;u<4;u++){
        float4 wv = *(const float4*)(wr + u*4);
        A[u].x  = fmaf(xa[jj],wv.x,A[u].x);  A[u].y  = fmaf(xa[jj],wv.y,A[u].y);
        A[u].z  = fmaf(xa[jj],wv.z,A[u].z);  A[u].w  = fmaf(xa[jj],wv.w,A[u].w);
        Bv[u].x = fmaf(xb_[jj],wv.x,Bv[u].x); Bv[u].y = fmaf(xb_[jj],wv.y,Bv[u].y);
        Bv[u].z = fmaf(xb_[jj],wv.z,Bv[u].z); Bv[u].w = fmaf(xb_[jj],wv.w,Bv[u].w);
      }
    }
  }
#pragma unroll
  for (int u=0;u<4;u++){
    float4 bkv = *(const float4*)(bk + mc + u*4);
    float4 ra, rb;
    ra.x = va ? A[u].x+bkv.x : bkv.x;  ra.y = va ? A[u].y+bkv.y : bkv.y;
    ra.z = va ? A[u].z+bkv.z : bkv.z;  ra.w = va ? A[u].w+bkv.w : bkv.w;
    rb.x = vb ? Bv[u].x+bkv.x : bkv.x; rb.y = vb ? Bv[u].y+bkv.y : bkv.y;
    rb.z = vb ? Bv[u].z+bkv.z : bkv.z; rb.w = vb ? Bv[u].w+bkv.w : bkv.w;
    *(float4*)(kp + ((size_t)b*T_+ta)*M_ + mc + u*4) = ra;
    *(float4*)(kp + ((size_t)b*T_+tb)*M_ + mc + u*4) = rb;
  }
}

// ---------------- attention ----------------
__global__ __launch_bounds__(256) void attn_kernel(
    const float* __restrict__ h2_all, const float* __restrict__ kp,
    const float* __restrict__ WqT, const float* __restrict__ bq,
    const int* __restrict__ slen, float* __restrict__ out)
{
  const int tid = threadIdx.x;
  const int b = blockIdx.x >> 5, scg = blockIdx.x & 31;
  const int s0 = scg*8;
  __shared__ float qL[8][64];
  __shared__ float red[8][4];
  const int wid = tid>>6, lane = tid&63;

  { // q = h2 @ Wq + bq
    const int jj = tid>>5, mh = tid&31;
    const float* hr = h2_all + ((size_t)(s0+jj)*B_ + b)*H_;
    const float* wa = WqT + (size_t)mh*256;
    const float* wb = WqT + (size_t)(mh+32)*256;
    float a0=0.f, a1=0.f;
    for (int k4=0;k4<64;k4++){
      float4 h4 = *(const float4*)(hr + k4*4);
      float4 v0 = *(const float4*)(wa + k4*4);
      float4 v1 = *(const float4*)(wb + k4*4);
      a0 += dot4(h4,v0);
      a1 += dot4(h4,v1);
    }
    qL[jj][mh]    = a0 + bq[mh];
    qL[jj][mh+32] = a1 + bq[mh+32];
  }
  __syncthreads();

  const int len = slen[b];
  float sc_[8][8];
#pragma unroll
  for (int ti=0; ti<8; ti++){
    const int t = ti*256 + tid;
    const float* kr = kp + ((size_t)b*T_ + t)*M_;
    float tmp[8];
#pragma unroll
    for (int jj=0;jj<8;jj++) tmp[jj]=0.f;
#pragma unroll
    for (int u4=0; u4<4; u4++){
      float4 k0 = *(const float4*)(kr + u4*16);
      float4 k1 = *(const float4*)(kr + u4*16 + 4);
      float4 k2 = *(const float4*)(kr + u4*16 + 8);
      float4 k3 = *(const float4*)(kr + u4*16 + 12);
#pragma unroll
      for (int jj=0;jj<8;jj++){
        const float4* q4 = (const float4*)&qL[jj][u4*16];
        tmp[jj] += dot4(k0,q4[0]) + dot4(k1,q4[1]) + dot4(k2,q4[2]) + dot4(k3,q4[3]);
      }
    }
    float bias = (t<len) ? 0.f : -1e9f;
#pragma unroll
    for (int jj=0;jj<8;jj++) sc_[ti][jj] = fmaf(tmp[jj], 0.125f, bias);
  }

  float mx[8];
#pragma unroll
  for (int jj=0;jj<8;jj++){
    float m = sc_[0][jj];
#pragma unroll
    for (int ti=1;ti<8;ti++) m = fmaxf(m, sc_[ti][jj]);
#pragma unroll
    for (int off=1; off<64; off<<=1) m = fmaxf(m, __shfl_xor(m, off));
    if (lane==0) red[jj][wid] = m;
  }
  __syncthreads();
#pragma unroll
  for (int jj=0;jj<8;jj++)
    mx[jj] = fmaxf(fmaxf(red[jj][0],red[jj][1]), fmaxf(red[jj][2],red[jj][3]));
  __syncthreads();
#pragma unroll
  for (int jj=0;jj<8;jj++){
    float s = 0.f;
#pragma unroll
    for (int ti=0;ti<8;ti++){
      float e = __expf(sc_[ti][jj] - mx[jj]);
      sc_[ti][jj] = e;
      s += e;
    }
#pragma unroll
    for (int off=1; off<64; off<<=1) s += __shfl_xor(s, off);
    if (lane==0) red[jj][wid] = s;
  }
  __syncthreads();
#pragma unroll
  for (int jj=0;jj<8;jj++){
    float r = 1.f/(red[jj][0]+red[jj][1]+red[jj][2]+red[jj][3]);
    float* o = out + ((size_t)b*L_ + s0 + jj)*T_;
#pragma unroll
    for (int ti=0;ti<8;ti++) o[ti*256 + tid] = sc_[ti][jj]*r;
  }
}

// ---------------- host ----------------
extern "C" void kernel_launch(void* const* d_in, const int* in_sizes, int n_in,
                              void* d_out, int out_size, void* d_ws, size_t ws_size,
                              hipStream_t stream) {
  (void)in_sizes; (void)n_in; (void)out_size;
  const float* seq  = (const float*)d_in[0];
  const int*   slen = (const int*)  d_in[1];
  const float* Wp   = (const float*)d_in[3];
  const float* bp   = (const float*)d_in[4];
  const float* Wihe = (const float*)d_in[5];
  const float* Whhe = (const float*)d_in[6];
  const float* bihe = (const float*)d_in[7];
  const float* bhhe = (const float*)d_in[8];
  const float* Wihd = (const float*)d_in[9];
  const float* Whhd = (const float*)d_in[10];
  const float* bihd = (const float*)d_in[11];
  const float* bhhd = (const float*)d_in[12];
  const float* Wq   = (const float*)d_in[13];
  const float* bq   = (const float*)d_in[14];
  const float* Wk   = (const float*)d_in[15];
  const float* bk   = (const float*)d_in[16];
  float* out = (float*)d_out;

  char* p = (char*)d_ws;
  auto take = [&](size_t bytes)->char* {
    char* r = p; p += (bytes + 255) & ~(size_t)255; return r;
  };
  float* h2_all = (float*)take((size_t)L_*B_*H_*4);          // 8 MB
  float* kproj  = (float*)take((size_t)B_*T_*M_*4);          // 16 MB
  float* cT     = (float*)take((size_t)B_*H_*4);
  float* W_dc   = (float*)take((size_t)G4_*H_*4);            // 1 MB
  float* Wc0    = (float*)take(G4_*4);
  float* Wc1    = (float*)take(G4_*4);
  float* bc     = (float*)take(G4_*4);
  float* b_dc   = (float*)take(G4_*4);
  float* WqT    = (float*)take((size_t)M_*H_*4);
  unsigned long long* ring_e = (unsigned long long*)take((size_t)NG_*RING_*1024*8); // 512 KB
  unsigned long long* ring_d = (unsigned long long*)take((size_t)NG_*RING_*1024*8); // 512 KB
  int* xb_e = (int*)take((size_t)NG_*NSL_*4);
  int* xb_d = (int*)take((size_t)NG_*NSL_*4);

  size_t used = (size_t)(p - (char*)d_ws);
  float* h_all;
  if (ws_size >= used + (size_t)T_*B_*H_*4) {
    h_all = (float*)take((size_t)T_*B_*H_*4);                // 64 MB
  } else {
    h_all = out;  // d_out is exactly T_*B_*H_ floats; dead before attn writes
  }

  // zero tag rings + detection buffers each launch (tags are 1..T so 0 never matches;
  // kernel-boundary flush/invalidate makes these zeros visible to all XCDs)
  hipMemsetAsync(ring_e, 0, (size_t)NG_*RING_*1024*8, stream);
  hipMemsetAsync(ring_d, 0, (size_t)NG_*RING_*1024*8, stream);
  hipMemsetAsync(xb_e,   0, (size_t)NG_*NSL_*4, stream);
  hipMemsetAsync(xb_d,   0, (size_t)NG_*NSL_*4, stream);

  prep_wdc  <<<G4_*H_/256, 256, 0, stream>>>(Wihd, Whhd, W_dc);
  prep_small<<<68, 256, 0, stream>>>(Wp, bp, Wihe, bihe, bhhe, bihd, bhhd, Wq,
                                     Wc0, Wc1, bc, b_dc, WqT);
  enc_kernel<<<NG_*NSL_, 1024, 0, stream>>>(seq, slen, Whhe, Wc0, Wc1, bc,
                                            h_all, cT, ring_e, xb_e);
  kproj_kernel<<<B_*16, 256, 0, stream>>>(h_all, slen, Wk, bk, kproj);
  dec_kernel<<<NG_*NSL_, 1024, 0, stream>>>(slen, W_dc, b_dc, h_all, cT,
                                            h2_all, ring_d, xb_d);
  attn_kernel<<<B_*32, 256, 0, stream>>>(h2_all, kproj, WqT, bq, slen, out);
}

// Round 8
// 7961.378 us; speedup vs baseline: 2.5144x; 2.5144x over previous
//
#include <hip/hip_runtime.h>
#include <stdint.h>

#define B_ 32
#define T_ 2048
#define H_ 256
#define M_ 64
#define L_ 256
#define G4_ 1024     // 4*H gate rows

#define NG_ 8        // batch groups (4 batches each)
#define NSL_ 16      // hidden slices per group
#define EPT_ 16      // h elements per slice
#define RING_ 8      // ring slots; block skew <=1 so reuse distance 8 is safe

__device__ __forceinline__ float sig_fast(float x){ return 1.f/(1.f+__expf(-x)); }
__device__ __forceinline__ float tanh_fast(float x){ return 2.f/(1.f+__expf(-2.f*x)) - 1.f; }
__device__ __forceinline__ float dot4(float4 a, float4 b){
  return fmaf(a.x,b.x, fmaf(a.y,b.y, fmaf(a.z,b.z, a.w*b.w)));
}
__device__ __forceinline__ unsigned long long ld_ag(const unsigned long long* p){
  return __hip_atomic_load(p, __ATOMIC_RELAXED, __HIP_MEMORY_SCOPE_AGENT);
}
// 4-deep rolling poll: keep 4 same-address loads in flight, test oldest, reissue.
// Sampling interval ~ Lf/4 instead of Lf -> discovery after visibility ~1.25*Lf.
__device__ __forceinline__ unsigned long long poll_roll(const unsigned long long* p,
                                                        unsigned tg){
  unsigned long long vA = ld_ag(p);
  unsigned long long vB = ld_ag(p);
  unsigned long long vC = ld_ag(p);
  unsigned long long vD = ld_ag(p);
  for(;;){
    if ((unsigned)(vA>>32) == tg) return vA;
    vA = ld_ag(p);
    if ((unsigned)(vB>>32) == tg) return vB;
    vB = ld_ag(p);
    if ((unsigned)(vC>>32) == tg) return vC;
    vC = ld_ag(p);
    if ((unsigned)(vD>>32) == tg) return vD;
    vD = ld_ag(p);
  }
}

// ---------------- prep kernels ----------------
__global__ void prep_wdc(const float* __restrict__ a, const float* __restrict__ b,
                         float* __restrict__ o){
  int i = blockIdx.x*256 + threadIdx.x;
  o[i] = a[i] + b[i];
}

__global__ void prep_small(const float* __restrict__ Wp, const float* __restrict__ bp,
                           const float* __restrict__ Wihe, const float* __restrict__ bihe,
                           const float* __restrict__ bhhe, const float* __restrict__ bihd,
                           const float* __restrict__ bhhd, const float* __restrict__ Wq,
                           float* __restrict__ Wc0, float* __restrict__ Wc1,
                           float* __restrict__ bc, float* __restrict__ bdc,
                           float* __restrict__ WqT){
  int idx = blockIdx.x*256 + threadIdx.x;
  if (idx < 16384){                 // WqT[m][k] = Wq[k][m]
    int m = idx >> 8, k = idx & 255;
    WqT[m*256 + k] = Wq[k*64 + m];
  } else if (idx < 16384 + 1024){   // fused input coeffs per gate row
    int j = idx - 16384;
    const float* wr = Wihe + j*256;
    float a0=0.f, a1=0.f, ab=0.f;
    for (int e=0;e<256;e++){
      float w = wr[e];
      a0 = fmaf(Wp[e],     w, a0);
      a1 = fmaf(Wp[256+e], w, a1);
      ab = fmaf(bp[e],     w, ab);
    }
    Wc0[j] = a0; Wc1[j] = a1;
    bc[j]  = ab + bihe[j] + bhhe[j];
    bdc[j] = bihd[j] + bhhd[j];
  }
}

// ---------------- encoder LSTM (persistent; fused-packet ring, rolling poll) ----------------
__global__ __launch_bounds__(1024) void enc_kernel(
    const float* __restrict__ seq, const int* __restrict__ slen,
    const float* __restrict__ Whh,
    const float* __restrict__ Wc0, const float* __restrict__ Wc1,
    const float* __restrict__ bc,
    float* __restrict__ h_all, float* __restrict__ cT,
    unsigned long long* __restrict__ ring)
{
  const int tid = threadIdx.x;
  const int grp = blockIdx.x & 7, slice = blockIdx.x >> 3;
  const int rp = tid >> 4, kc = tid & 15;
  const int j = ((rp >> 4) << 8) + slice*EPT_ + (rp & 15);   // gate*256 + slice*16 + elem
  float4 w0 = *(const float4*)(Whh + (size_t)j*256 +   0 + kc*4);
  float4 w1 = *(const float4*)(Whh + (size_t)j*256 +  64 + kc*4);
  float4 w2 = *(const float4*)(Whh + (size_t)j*256 + 128 + kc*4);
  float4 w3 = *(const float4*)(Whh + (size_t)j*256 + 192 + kc*4);
  float c0 = Wc0[j], c1 = Wc1[j], cbv = bc[j];

  __shared__ float hbuf[4][256];
  __shared__ float sbuf[4][2];
  __shared__ float gbuf[4][64];

  const int ub = tid >> 4, ue = tid & 15;       // updater mapping (tid<64)
  float creg = 0.f;
  int myb = 0, mylen = -1;
  if (tid < 64){ myb = grp + 8*ub; mylen = slen[myb]; }

  const int ib = tid >> 8, ik = tid & 255;      // consumer mapping: batch, elem
  const bool poller = ((ik >> 4) != slice);     // own slice arrives via LDS short-circuit
  unsigned long long* ringg = ring + (size_t)grp * (RING_*1024);

  for (int t = 0; t < T_; ++t){
    if (tid < 8) sbuf[tid>>1][tid&1] = seq[((size_t)(grp + 8*(tid>>1))*T_ + t)*2 + (tid&1)];

    if (t == 0){
      hbuf[ib][ik] = 0.f;
    } else if (poller){
      const unsigned long long* pp = ringg + (size_t)((t-1) & (RING_-1))*1024 + tid;
      unsigned long long v = poll_roll(pp, (unsigned)t);
      hbuf[ib][ik] = __uint_as_float((unsigned)v);
    }
    __syncthreads();  // B1: hbuf/sbuf ready

#pragma unroll
    for (int i = 0; i < 4; ++i){
      float4 h0 = *(const float4*)&hbuf[i][       kc*4];
      float4 h1 = *(const float4*)&hbuf[i][ 64 + kc*4];
      float4 h2 = *(const float4*)&hbuf[i][128 + kc*4];
      float4 h3 = *(const float4*)&hbuf[i][192 + kc*4];
      float a = dot4(w0,h0) + dot4(w1,h1) + dot4(w2,h2) + dot4(w3,h3);
#pragma unroll
      for (int off = 1; off < 16; off <<= 1) a += __shfl_xor(a, off);
      if (kc == 0)
        gbuf[i][rp] = fmaf(sbuf[i][0], c0, fmaf(sbuf[i][1], c1, a + cbv));
    }
    __syncthreads();  // B2: gbuf ready

    if (tid < 64){
      float gi = gbuf[ub][      ue];
      float gf = gbuf[ub][16 + ue];
      float gg = gbuf[ub][32 + ue];
      float go = gbuf[ub][48 + ue];
      creg = sig_fast(gf)*creg + sig_fast(gi)*tanh_fast(gg);
      float h = sig_fast(go)*tanh_fast(creg);
      unsigned long long pk = ((unsigned long long)(unsigned)(t+1) << 32)
                            | (unsigned long long)__float_as_uint(h);
      // publish FIRST (critical path), then local/off-path writes
      __hip_atomic_store(ringg + (size_t)(t & (RING_-1))*1024 + ub*256 + slice*EPT_ + ue,
                         pk, __ATOMIC_RELAXED, __HIP_MEMORY_SCOPE_AGENT);
      hbuf[ub][slice*EPT_ + ue] = h;                            // own-slice short-circuit
      h_all[((size_t)t*B_ + myb)*H_ + slice*EPT_ + ue] = h;     // off critical path
      if (t == mylen - 1) cT[myb*H_ + slice*EPT_ + ue] = creg;
    }
    // next-iter staging writes only remote hbuf regions; compute waits at B1
  }
}

// ---------------- decoder LSTM (x == h, folded weights) ----------------
__global__ __launch_bounds__(1024) void dec_kernel(
    const int* __restrict__ slen,
    const float* __restrict__ Wdc, const float* __restrict__ bdc,
    const float* __restrict__ h_all, const float* __restrict__ cT,
    float* __restrict__ h2_all, unsigned long long* __restrict__ ring)
{
  const int tid = threadIdx.x;
  const int grp = blockIdx.x & 7, slice = blockIdx.x >> 3;
  const int rp = tid >> 4, kc = tid & 15;
  const int j = ((rp >> 4) << 8) + slice*EPT_ + (rp & 15);
  float4 w0 = *(const float4*)(Wdc + (size_t)j*256 +   0 + kc*4);
  float4 w1 = *(const float4*)(Wdc + (size_t)j*256 +  64 + kc*4);
  float4 w2 = *(const float4*)(Wdc + (size_t)j*256 + 128 + kc*4);
  float4 w3 = *(const float4*)(Wdc + (size_t)j*256 + 192 + kc*4);
  float cbv = bdc[j];

  __shared__ float hbuf[4][256];
  __shared__ float gbuf[4][64];

  const int ub = tid >> 4, ue = tid & 15;
  float creg = 0.f; int myb = 0;
  if (tid < 64){ myb = grp + 8*ub; creg = cT[myb*H_ + slice*EPT_ + ue]; }

  const int tb = tid >> 7, kp = tid & 127;      // s==0 bulk-stage mapping (tid<512)
  const int stage_b = grp + 8*tb;
  int stage_len = 1;
  if (tid < 512) stage_len = slen[stage_b];

  const int ib = tid >> 8, ik = tid & 255;
  const bool poller = ((ik >> 4) != slice);
  unsigned long long* ringg = ring + (size_t)grp * (RING_*1024);

  for (int s = 0; s < L_; ++s){
    if (s == 0){
      if (tid < 512)   // h_all fully written by completed enc kernel: plain loads OK
        *(float2*)&hbuf[tb][kp*2] =
            *(const float2*)(h_all + ((size_t)(stage_len-1)*B_ + stage_b)*H_ + kp*2);
    } else if (poller){
      const unsigned long long* pp = ringg + (size_t)((s-1) & (RING_-1))*1024 + tid;
      unsigned long long v = poll_roll(pp, (unsigned)s);
      hbuf[ib][ik] = __uint_as_float((unsigned)v);
    }
    __syncthreads();  // B1

#pragma unroll
    for (int i = 0; i < 4; ++i){
      float4 h0 = *(const float4*)&hbuf[i][       kc*4];
      float4 h1 = *(const float4*)&hbuf[i][ 64 + kc*4];
      float4 h2 = *(const float4*)&hbuf[i][128 + kc*4];
      float4 h3 = *(const float4*)&hbuf[i][192 + kc*4];
      float a = dot4(w0,h0) + dot4(w1,h1) + dot4(w2,h2) + dot4(w3,h3);
#pragma unroll
      for (int off = 1; off < 16; off <<= 1) a += __shfl_xor(a, off);
      if (kc == 0) gbuf[i][rp] = a + cbv;
    }
    __syncthreads();  // B2

    if (tid < 64){
      float gi = gbuf[ub][      ue];
      float gf = gbuf[ub][16 + ue];
      float gg = gbuf[ub][32 + ue];
      float go = gbuf[ub][48 + ue];
      creg = sig_fast(gf)*creg + sig_fast(gi)*tanh_fast(gg);
      float h = sig_fast(go)*tanh_fast(creg);
      unsigned long long pk = ((unsigned long long)(unsigned)(s+1) << 32)
                            | (unsigned long long)__float_as_uint(h);
      __hip_atomic_store(ringg + (size_t)(s & (RING_-1))*1024 + ub*256 + slice*EPT_ + ue,
                         pk, __ATOMIC_RELAXED, __HIP_MEMORY_SCOPE_AGENT);
      hbuf[ub][slice*EPT_ + ue] = h;                            // own-slice short-circuit
      h2_all[((size_t)s*B_ + myb)*H_ + slice*EPT_ + ue] = h;
    }
  }
}

// ---------------- kproj = masked(enc) @ Wk + bk ----------------
__global__ __launch_bounds__(256) void kproj_kernel(
    const float* __restrict__ h_all, const int* __restrict__ slen,
    const float* __restrict__ Wk, const float* __restrict__ bk,
    float* __restrict__ kp)
{
  __shared__ float wk[256*64];
  const int tid = threadIdx.x;
  const int b = blockIdx.x >> 4, tc = blockIdx.x & 15;
  const int t0 = tc*128;
#pragma unroll
  for (int i=0;i<16;i++){
    int idx = tid + i*256;
    *(float4*)(&wk[idx*4]) = *(const float4*)(Wk + idx*4);
  }
  __syncthreads();
  const int tp = tid>>2, mc = (tid&3)*16;
  const int ta = t0 + tp*2, tb = ta+1;
  const int len = slen[b];
  const bool va = ta < len, vb = tb < len;
  const float* ha = h_all + ((size_t)ta*B_ + b)*H_;
  const float* hb = h_all + ((size_t)tb*B_ + b)*H_;
  float4 A[4], Bv[4];
#pragma unroll
  for (int u=0;u<4;u++){ A[u].x=A[u].y=A[u].z=A[u].w=0.f; Bv[u]=A[u]; }

  for (int k4=0;k4<64;k4++){
    float xa[4], xb_[4];
    if (va){ float4 v = *(const float4*)(ha + k4*4); xa[0]=v.x; xa[1]=v.y; xa[2]=v.z; xa[3]=v.w; }
    else   { xa[0]=xa[1]=xa[2]=xa[3]=0.f; }
    if (vb){ float4 v = *(const float4*)(hb + k4*4); xb_[0]=v.x; xb_[1]=v.y; xb_[2]=v.z; xb_[3]=v.w; }
    else   { xb_[0]=xb_[1]=xb_[2]=xb_[3]=0.f; }
#pragma unroll
    for (int jj=0;jj<4;jj++){
      const float* wr = &wk[(k4*4+jj)*64 + mc];
#pragma unroll
      for (int u=0;u<4;u++){
        float4 wv = *(const float4*)(wr + u*4);
        A[u].x  = fmaf(xa[jj],wv.x,A[u].x);  A[u].y  = fmaf(xa[jj],wv.y,A[u].y);
        A[u].z  = fmaf(xa[jj],wv.z,A[u].z);  A[u].w  = fmaf(xa[jj],wv.w,A[u].w);
        Bv[u].x = fmaf(xb_[jj],wv.x,Bv[u].x); Bv[u].y = fmaf(xb_[jj],wv.y,Bv[u].y);
        Bv[u].z = fmaf(xb_[jj],wv.z,Bv[u].z); Bv[u].w = fmaf(xb_[jj],wv.w,Bv[u].w);
      }
    }
  }
#pragma unroll
  for (int u=0;u<4;u++){
    float4 bkv = *(const float4*)(bk + mc + u*4);
    float4 ra, rb;
    ra.x = va ? A[u].x+bkv.x : bkv.x;  ra.y = va ? A[u].y+bkv.y : bkv.y;
    ra.z = va ? A[u].z+bkv.z : bkv.z;  ra.w = va ? A[u].w+bkv.w : bkv.w;
    rb.x = vb ? Bv[u].x+bkv.x : bkv.x; rb.y = vb ? Bv[u].y+bkv.y : bkv.y;
    rb.z = vb ? Bv[u].z+bkv.z : bkv.z; rb.w = vb ? Bv[u].w+bkv.w : bkv.w;
    *(float4*)(kp + ((size_t)b*T_+ta)*M_ + mc + u*4) = ra;
    *(float4*)(kp + ((size_t)b*T_+tb)*M_ + mc + u*4) = rb;
  }
}

// ---------------- attention ----------------
__global__ __launch_bounds__(256) void attn_kernel(
    const float* __restrict__ h2_all, const float* __restrict__ kp,
    const float* __restrict__ WqT, const float* __restrict__ bq,
    const int* __restrict__ slen, float* __restrict__ out)
{
  const int tid = threadIdx.x;
  const int b = blockIdx.x >> 5, scg = blockIdx.x & 31;
  const int s0 = scg*8;
  __shared__ float qL[8][64];
  __shared__ float red[8][4];
  const int wid = tid>>6, lane = tid&63;

  { // q = h2 @ Wq + bq
    const int jj = tid>>5, mh = tid&31;
    const float* hr = h2_all + ((size_t)(s0+jj)*B_ + b)*H_;
    const float* wa = WqT + (size_t)mh*256;
    const float* wb = WqT + (size_t)(mh+32)*256;
    float a0=0.f, a1=0.f;
    for (int k4=0;k4<64;k4++){
      float4 h4 = *(const float4*)(hr + k4*4);
      float4 v0 = *(const float4*)(wa + k4*4);
      float4 v1 = *(const float4*)(wb + k4*4);
      a0 += dot4(h4,v0);
      a1 += dot4(h4,v1);
    }
    qL[jj][mh]    = a0 + bq[mh];
    qL[jj][mh+32] = a1 + bq[mh+32];
  }
  __syncthreads();

  const int len = slen[b];
  float sc_[8][8];
#pragma unroll
  for (int ti=0; ti<8; ti++){
    const int t = ti*256 + tid;
    const float* kr = kp + ((size_t)b*T_ + t)*M_;
    float tmp[8];
#pragma unroll
    for (int jj=0;jj<8;jj++) tmp[jj]=0.f;
#pragma unroll
    for (int u4=0; u4<4; u4++){
      float4 k0 = *(const float4*)(kr + u4*16);
      float4 k1 = *(const float4*)(kr + u4*16 + 4);
      float4 k2 = *(const float4*)(kr + u4*16 + 8);
      float4 k3 = *(const float4*)(kr + u4*16 + 12);
#pragma unroll
      for (int jj=0;jj<8;jj++){
        const float4* q4 = (const float4*)&qL[jj][u4*16];
        tmp[jj] += dot4(k0,q4[0]) + dot4(k1,q4[1]) + dot4(k2,q4[2]) + dot4(k3,q4[3]);
      }
    }
    float bias = (t<len) ? 0.f : -1e9f;
#pragma unroll
    for (int jj=0;jj<8;jj++) sc_[ti][jj] = fmaf(tmp[jj], 0.125f, bias);
  }

  float mx[8];
#pragma unroll
  for (int jj=0;jj<8;jj++){
    float m = sc_[0][jj];
#pragma unroll
    for (int ti=1;ti<8;ti++) m = fmaxf(m, sc_[ti][jj]);
#pragma unroll
    for (int off=1; off<64; off<<=1) m = fmaxf(m, __shfl_xor(m, off));
    if (lane==0) red[jj][wid] = m;
  }
  __syncthreads();
#pragma unroll
  for (int jj=0;jj<8;jj++)
    mx[jj] = fmaxf(fmaxf(red[jj][0],red[jj][1]), fmaxf(red[jj][2],red[jj][3]));
  __syncthreads();
#pragma unroll
  for (int jj=0;jj<8;jj++){
    float s = 0.f;
#pragma unroll
    for (int ti=0;ti<8;ti++){
      float e = __expf(sc_[ti][jj] - mx[jj]);
      sc_[ti][jj] = e;
      s += e;
    }
#pragma unroll
    for (int off=1; off<64; off<<=1) s += __shfl_xor(s, off);
    if (lane==0) red[jj][wid] = s;
  }
  __syncthreads();
#pragma unroll
  for (int jj=0;jj<8;jj++){
    float r = 1.f/(red[jj][0]+red[jj][1]+red[jj][2]+red[jj][3]);
    float* o = out + ((size_t)b*L_ + s0 + jj)*T_;
#pragma unroll
    for (int ti=0;ti<8;ti++) o[ti*256 + tid] = sc_[ti][jj]*r;
  }
}

// ---------------- host ----------------
extern "C" void kernel_launch(void* const* d_in, const int* in_sizes, int n_in,
                              void* d_out, int out_size, void* d_ws, size_t ws_size,
                              hipStream_t stream) {
  (void)in_sizes; (void)n_in; (void)out_size;
  const float* seq  = (const float*)d_in[0];
  const int*   slen = (const int*)  d_in[1];
  const float* Wp   = (const float*)d_in[3];
  const float* bp   = (const float*)d_in[4];
  const float* Wihe = (const float*)d_in[5];
  const float* Whhe = (const float*)d_in[6];
  const float* bihe = (const float*)d_in[7];
  const float* bhhe = (const float*)d_in[8];
  const float* Wihd = (const float*)d_in[9];
  const float* Whhd = (const float*)d_in[10];
  const float* bihd = (const float*)d_in[11];
  const float* bhhd = (const float*)d_in[12];
  const float* Wq   = (const float*)d_in[13];
  const float* bq   = (const float*)d_in[14];
  const float* Wk   = (const float*)d_in[15];
  const float* bk   = (const float*)d_in[16];
  float* out = (float*)d_out;

  char* p = (char*)d_ws;
  auto take = [&](size_t bytes)->char* {
    char* r = p; p += (bytes + 255) & ~(size_t)255; return r;
  };
  float* h2_all = (float*)take((size_t)L_*B_*H_*4);          // 8 MB
  float* kproj  = (float*)take((size_t)B_*T_*M_*4);          // 16 MB
  float* cT     = (float*)take((size_t)B_*H_*4);
  float* W_dc   = (float*)take((size_t)G4_*H_*4);            // 1 MB
  float* Wc0    = (float*)take(G4_*4);
  float* Wc1    = (float*)take(G4_*4);
  float* bc     = (float*)take(G4_*4);
  float* b_dc   = (float*)take(G4_*4);
  float* WqT    = (float*)take((size_t)M_*H_*4);
  unsigned long long* ring_e = (unsigned long long*)take((size_t)NG_*RING_*1024*8); // 512 KB
  unsigned long long* ring_d = (unsigned long long*)take((size_t)NG_*RING_*1024*8); // 512 KB

  size_t used = (size_t)(p - (char*)d_ws);
  float* h_all;
  if (ws_size >= used + (size_t)T_*B_*H_*4) {
    h_all = (float*)take((size_t)T_*B_*H_*4);                // 64 MB
  } else {
    h_all = out;  // d_out is exactly T_*B_*H_ floats; dead before attn writes
  }

  // zero tag rings each launch (tags are 1..T so 0 never matches; replay-safe)
  hipMemsetAsync(ring_e, 0, (size_t)NG_*RING_*1024*8, stream);
  hipMemsetAsync(ring_d, 0, (size_t)NG_*RING_*1024*8, stream);

  prep_wdc  <<<G4_*H_/256, 256, 0, stream>>>(Wihd, Whhd, W_dc);
  prep_small<<<68, 256, 0, stream>>>(Wp, bp, Wihe, bihe, bhhe, bihd, bhhd, Wq,
                                     Wc0, Wc1, bc, b_dc, WqT);
  enc_kernel<<<NG_*NSL_, 1024, 0, stream>>>(seq, slen, Whhe, Wc0, Wc1, bc,
                                            h_all, cT, ring_e);
  kproj_kernel<<<B_*16, 256, 0, stream>>>(h_all, slen, Wk, bk, kproj);
  dec_kernel<<<NG_*NSL_, 1024, 0, stream>>>(slen, W_dc, b_dc, h_all, cT,
                                            h2_all, ring_d);
  attn_kernel<<<B_*32, 256, 0, stream>>>(h2_all, kproj, WqT, bq, slen, out);
}

// Round 9
// 7655.553 us; speedup vs baseline: 2.6149x; 1.0399x over previous
//
#include <hip/hip_runtime.h>
#include <stdint.h>

#define B_ 32
#define T_ 2048
#define H_ 256
#define M_ 64
#define L_ 256
#define G4_ 1024     // 4*H gate rows

#define NG_ 8        // batch groups (4 batches each)
#define NSL_ 16      // hidden slices per group
#define EPT_ 16      // h elements per slice
#define RING_ 8      // ring slots; block skew <=1 so reuse distance 8 is safe

__device__ __forceinline__ float sig_fast(float x){ return 1.f/(1.f+__expf(-x)); }
__device__ __forceinline__ float tanh_fast(float x){ return 2.f/(1.f+__expf(-2.f*x)) - 1.f; }
__device__ __forceinline__ float dot4(float4 a, float4 b){
  return fmaf(a.x,b.x, fmaf(a.y,b.y, fmaf(a.z,b.z, a.w*b.w)));
}
__device__ __forceinline__ unsigned long long ld_ag(const unsigned long long* p){
  return __hip_atomic_load(p, __ATOMIC_RELAXED, __HIP_MEMORY_SCOPE_AGENT);
}

// ---------------- prep kernels ----------------
__global__ void prep_wdc(const float* __restrict__ a, const float* __restrict__ b,
                         float* __restrict__ o){
  int i = blockIdx.x*256 + threadIdx.x;
  o[i] = a[i] + b[i];
}

__global__ void prep_small(const float* __restrict__ Wp, const float* __restrict__ bp,
                           const float* __restrict__ Wihe, const float* __restrict__ bihe,
                           const float* __restrict__ bhhe, const float* __restrict__ bihd,
                           const float* __restrict__ bhhd, const float* __restrict__ Wq,
                           float* __restrict__ Wc0, float* __restrict__ Wc1,
                           float* __restrict__ bc, float* __restrict__ bdc,
                           float* __restrict__ WqT){
  int idx = blockIdx.x*256 + threadIdx.x;
  if (idx < 16384){                 // WqT[m][k] = Wq[k][m]
    int m = idx >> 8, k = idx & 255;
    WqT[m*256 + k] = Wq[k*64 + m];
  } else if (idx < 16384 + 1024){   // fused input coeffs per gate row
    int j = idx - 16384;
    const float* wr = Wihe + j*256;
    float a0=0.f, a1=0.f, ab=0.f;
    for (int e=0;e<256;e++){
      float w = wr[e];
      a0 = fmaf(Wp[e],     w, a0);
      a1 = fmaf(Wp[256+e], w, a1);
      ab = fmaf(bp[e],     w, ab);
    }
    Wc0[j] = a0; Wc1[j] = a1;
    bc[j]  = ab + bihe[j] + bhhe[j];
    bdc[j] = bihd[j] + bhhd[j];
  }
}

// ---------- encoder LSTM: fused per-element gates, 1 barrier/step ----------
// 16-lane group owns (batch ib, h-elem hofs): computes all 4 gate dots, lane 0
// updates c/h in-lane and publishes the fused {tag,h} packet (R4-proven sync).
__global__ __launch_bounds__(1024) void enc_kernel(
    const float* __restrict__ seq, const int* __restrict__ slen,
    const float* __restrict__ Whh,
    const float* __restrict__ Wc0, const float* __restrict__ Wc1,
    const float* __restrict__ bc,
    float* __restrict__ h_all, float* __restrict__ cT,
    unsigned long long* __restrict__ ring)
{
  const int tid = threadIdx.x;
  const int grp = blockIdx.x & 7, slice = blockIdx.x >> 3;
  const int kc = tid & 15, gid = tid >> 4;
  const int ib = gid >> 4, ue = gid & 15;
  const int hofs = slice*EPT_ + ue;
  const int myb = grp + 8*ib;
  const int mylen = slen[myb];

  float4 wv[4][4];                 // 4 gates x 4 k-chunks (64 VGPR)
#pragma unroll
  for (int g=0; g<4; ++g){
    const float* wr = Whh + (size_t)(g*256 + hofs)*256;
#pragma unroll
    for (int u=0; u<4; ++u) wv[g][u] = *(const float4*)(wr + u*64 + kc*4);
  }
  float c0g[4], c1g[4], cbg[4];
#pragma unroll
  for (int g=0; g<4; ++g){
    int j = g*256 + hofs;
    c0g[g] = Wc0[j]; c1g[g] = Wc1[j]; cbg[g] = bc[j];
  }
  float creg = 0.f;

  __shared__ float hbuf[2][4][256];
  __shared__ float sbuf[2][4][2];
  const int pib = tid >> 8, pik = tid & 255;     // poller mapping
  const bool pol = ((pik >> 4) != slice);        // own slice via LDS short-circuit
  unsigned long long* ringg = ring + (size_t)grp * (RING_*1024);

  // t=0 state
  hbuf[0][pib][pik] = 0.f;
  if (tid < 8) sbuf[0][tid>>1][tid&1] = seq[((size_t)(grp + 8*(tid>>1))*T_ + 0)*2 + (tid&1)];
  __syncthreads();

  for (int t = 0; t < T_; ++t){
    const int cur = t & 1;
    // prefetch next step's seq inputs into the other buffer
    if (tid < 8 && t+1 < T_)
      sbuf[cur^1][tid>>1][tid&1] = seq[((size_t)(grp + 8*(tid>>1))*T_ + (t+1))*2 + (tid&1)];

    // ---- gate dots: h loaded once per lane, reused across 4 gates ----
    float4 h4[4];
#pragma unroll
    for (int u=0; u<4; ++u) h4[u] = *(const float4*)&hbuf[cur][ib][u*64 + kc*4];
    float a0 = dot4(wv[0][0],h4[0]) + dot4(wv[0][1],h4[1]) + dot4(wv[0][2],h4[2]) + dot4(wv[0][3],h4[3]);
    float a1 = dot4(wv[1][0],h4[0]) + dot4(wv[1][1],h4[1]) + dot4(wv[1][2],h4[2]) + dot4(wv[1][3],h4[3]);
    float a2 = dot4(wv[2][0],h4[0]) + dot4(wv[2][1],h4[1]) + dot4(wv[2][2],h4[2]) + dot4(wv[2][3],h4[3]);
    float a3 = dot4(wv[3][0],h4[0]) + dot4(wv[3][1],h4[1]) + dot4(wv[3][2],h4[2]) + dot4(wv[3][3],h4[3]);
#pragma unroll
    for (int off = 1; off < 16; off <<= 1){
      a0 += __shfl_xor(a0, off);
      a1 += __shfl_xor(a1, off);
      a2 += __shfl_xor(a2, off);
      a3 += __shfl_xor(a3, off);
    }

    // ---- in-lane update + publish (lane 0 of each 16-lane group) ----
    if (kc == 0){
      float s0 = sbuf[cur][ib][0], s1 = sbuf[cur][ib][1];
      float gi = fmaf(s0,c0g[0], fmaf(s1,c1g[0], a0 + cbg[0]));
      float gf = fmaf(s0,c0g[1], fmaf(s1,c1g[1], a1 + cbg[1]));
      float gg = fmaf(s0,c0g[2], fmaf(s1,c1g[2], a2 + cbg[2]));
      float go = fmaf(s0,c0g[3], fmaf(s1,c1g[3], a3 + cbg[3]));
      creg = sig_fast(gf)*creg + sig_fast(gi)*tanh_fast(gg);
      float h = sig_fast(go)*tanh_fast(creg);
      unsigned long long pk = ((unsigned long long)(unsigned)(t+1) << 32)
                            | (unsigned long long)__float_as_uint(h);
      __hip_atomic_store(ringg + (size_t)(t & (RING_-1))*1024 + ib*256 + hofs,
                         pk, __ATOMIC_RELAXED, __HIP_MEMORY_SCOPE_AGENT);
      hbuf[cur^1][ib][hofs] = h;                              // own-slice short-circuit
      h_all[((size_t)t*B_ + myb)*H_ + hofs] = h;              // off critical path
      if (t == mylen - 1) cT[myb*H_ + hofs] = creg;
    }

    // ---- poll next step's remote h into the other buffer ----
    if (t+1 < T_ && pol){
      const unsigned long long* pp = ringg + (size_t)(t & (RING_-1))*1024 + tid;
      const unsigned tg = (unsigned)(t+1);
      unsigned long long v;
      do { v = ld_ag(pp); } while ((unsigned)(v >> 32) != tg);
      hbuf[cur^1][pib][pik] = __uint_as_float((unsigned)v);
    }
    __syncthreads();   // single barrier per step
  }
}

// ---------- decoder LSTM: same fused structure (x == h, folded weights) ----------
__global__ __launch_bounds__(1024) void dec_kernel(
    const int* __restrict__ slen,
    const float* __restrict__ Wdc, const float* __restrict__ bdc,
    const float* __restrict__ h_all, const float* __restrict__ cT,
    float* __restrict__ h2_all, unsigned long long* __restrict__ ring)
{
  const int tid = threadIdx.x;
  const int grp = blockIdx.x & 7, slice = blockIdx.x >> 3;
  const int kc = tid & 15, gid = tid >> 4;
  const int ib = gid >> 4, ue = gid & 15;
  const int hofs = slice*EPT_ + ue;
  const int myb = grp + 8*ib;

  float4 wv[4][4];
#pragma unroll
  for (int g=0; g<4; ++g){
    const float* wr = Wdc + (size_t)(g*256 + hofs)*256;
#pragma unroll
    for (int u=0; u<4; ++u) wv[g][u] = *(const float4*)(wr + u*64 + kc*4);
  }
  float cbg[4];
#pragma unroll
  for (int g=0; g<4; ++g) cbg[g] = bdc[g*256 + hofs];
  float creg = cT[myb*H_ + hofs];   // only lane 0 uses it

  __shared__ float hbuf[2][4][256];
  const int pib = tid >> 8, pik = tid & 255;
  const bool pol = ((pik >> 4) != slice);
  unsigned long long* ringg = ring + (size_t)grp * (RING_*1024);

  // s=0 state: hT from completed enc kernel (plain loads OK)
  {
    const int blen = slen[grp + 8*pib];
    hbuf[0][pib][pik] = h_all[((size_t)(blen-1)*B_ + (grp + 8*pib))*H_ + pik];
  }
  __syncthreads();

  for (int s = 0; s < L_; ++s){
    const int cur = s & 1;
    float4 h4[4];
#pragma unroll
    for (int u=0; u<4; ++u) h4[u] = *(const float4*)&hbuf[cur][ib][u*64 + kc*4];
    float a0 = dot4(wv[0][0],h4[0]) + dot4(wv[0][1],h4[1]) + dot4(wv[0][2],h4[2]) + dot4(wv[0][3],h4[3]);
    float a1 = dot4(wv[1][0],h4[0]) + dot4(wv[1][1],h4[1]) + dot4(wv[1][2],h4[2]) + dot4(wv[1][3],h4[3]);
    float a2 = dot4(wv[2][0],h4[0]) + dot4(wv[2][1],h4[1]) + dot4(wv[2][2],h4[2]) + dot4(wv[2][3],h4[3]);
    float a3 = dot4(wv[3][0],h4[0]) + dot4(wv[3][1],h4[1]) + dot4(wv[3][2],h4[2]) + dot4(wv[3][3],h4[3]);
#pragma unroll
    for (int off = 1; off < 16; off <<= 1){
      a0 += __shfl_xor(a0, off);
      a1 += __shfl_xor(a1, off);
      a2 += __shfl_xor(a2, off);
      a3 += __shfl_xor(a3, off);
    }

    if (kc == 0){
      float gi = a0 + cbg[0], gf = a1 + cbg[1], gg = a2 + cbg[2], go = a3 + cbg[3];
      creg = sig_fast(gf)*creg + sig_fast(gi)*tanh_fast(gg);
      float h = sig_fast(go)*tanh_fast(creg);
      unsigned long long pk = ((unsigned long long)(unsigned)(s+1) << 32)
                            | (unsigned long long)__float_as_uint(h);
      __hip_atomic_store(ringg + (size_t)(s & (RING_-1))*1024 + ib*256 + hofs,
                         pk, __ATOMIC_RELAXED, __HIP_MEMORY_SCOPE_AGENT);
      hbuf[cur^1][ib][hofs] = h;
      h2_all[((size_t)s*B_ + myb)*H_ + hofs] = h;
    }

    if (s+1 < L_ && pol){
      const unsigned long long* pp = ringg + (size_t)(s & (RING_-1))*1024 + tid;
      const unsigned tg = (unsigned)(s+1);
      unsigned long long v;
      do { v = ld_ag(pp); } while ((unsigned)(v >> 32) != tg);
      hbuf[cur^1][pib][pik] = __uint_as_float((unsigned)v);
    }
    __syncthreads();
  }
}

// ---------------- kproj = masked(enc) @ Wk + bk ----------------
__global__ __launch_bounds__(256) void kproj_kernel(
    const float* __restrict__ h_all, const int* __restrict__ slen,
    const float* __restrict__ Wk, const float* __restrict__ bk,
    float* __restrict__ kp)
{
  __shared__ float wk[256*64];
  const int tid = threadIdx.x;
  const int b = blockIdx.x >> 4, tc = blockIdx.x & 15;
  const int t0 = tc*128;
#pragma unroll
  for (int i=0;i<16;i++){
    int idx = tid + i*256;
    *(float4*)(&wk[idx*4]) = *(const float4*)(Wk + idx*4);
  }
  __syncthreads();
  const int tp = tid>>2, mc = (tid&3)*16;
  const int ta = t0 + tp*2, tb = ta+1;
  const int len = slen[b];
  const bool va = ta < len, vb = tb < len;
  const float* ha = h_all + ((size_t)ta*B_ + b)*H_;
  const float* hb = h_all + ((size_t)tb*B_ + b)*H_;
  float4 A[4], Bv[4];
#pragma unroll
  for (int u=0;u<4;u++){ A[u].x=A[u].y=A[u].z=A[u].w=0.f; Bv[u]=A[u]; }

  for (int k4=0;k4<64;k4++){
    float xa[4], xb_[4];
    if (va){ float4 v = *(const float4*)(ha + k4*4); xa[0]=v.x; xa[1]=v.y; xa[2]=v.z; xa[3]=v.w; }
    else   { xa[0]=xa[1]=xa[2]=xa[3]=0.f; }
    if (vb){ float4 v = *(const float4*)(hb + k4*4); xb_[0]=v.x; xb_[1]=v.y; xb_[2]=v.z; xb_[3]=v.w; }
    else   { xb_[0]=xb_[1]=xb_[2]=xb_[3]=0.f; }
#pragma unroll
    for (int jj=0;jj<4;jj++){
      const float* wr = &wk[(k4*4+jj)*64 + mc];
#pragma unroll
      for (int u=0;u<4;u++){
        float4 wv = *(const float4*)(wr + u*4);
        A[u].x  = fmaf(xa[jj],wv.x,A[u].x);  A[u].y  = fmaf(xa[jj],wv.y,A[u].y);
        A[u].z  = fmaf(xa[jj],wv.z,A[u].z);  A[u].w  = fmaf(xa[jj],wv.w,A[u].w);
        Bv[u].x = fmaf(xb_[jj],wv.x,Bv[u].x); Bv[u].y = fmaf(xb_[jj],wv.y,Bv[u].y);
        Bv[u].z = fmaf(xb_[jj],wv.z,Bv[u].z); Bv[u].w = fmaf(xb_[jj],wv.w,Bv[u].w);
      }
    }
  }
#pragma unroll
  for (int u=0;u<4;u++){
    float4 bkv = *(const float4*)(bk + mc + u*4);
    float4 ra, rb;
    ra.x = va ? A[u].x+bkv.x : bkv.x;  ra.y = va ? A[u].y+bkv.y : bkv.y;
    ra.z = va ? A[u].z+bkv.z : bkv.z;  ra.w = va ? A[u].w+bkv.w : bkv.w;
    rb.x = vb ? Bv[u].x+bkv.x : bkv.x; rb.y = vb ? Bv[u].y+bkv.y : bkv.y;
    rb.z = vb ? Bv[u].z+bkv.z : bkv.z; rb.w = vb ? Bv[u].w+bkv.w : bkv.w;
    *(float4*)(kp + ((size_t)b*T_+ta)*M_ + mc + u*4) = ra;
    *(float4*)(kp + ((size_t)b*T_+tb)*M_ + mc + u*4) = rb;
  }
}

// ---------------- attention ----------------
__global__ __launch_bounds__(256) void attn_kernel(
    const float* __restrict__ h2_all, const float* __restrict__ kp,
    const float* __restrict__ WqT, const float* __restrict__ bq,
    const int* __restrict__ slen, float* __restrict__ out)
{
  const int tid = threadIdx.x;
  const int b = blockIdx.x >> 5, scg = blockIdx.x & 31;
  const int s0 = scg*8;
  __shared__ float qL[8][64];
  __shared__ float red[8][4];
  const int wid = tid>>6, lane = tid&63;

  { // q = h2 @ Wq + bq
    const int jj = tid>>5, mh = tid&31;
    const float* hr = h2_all + ((size_t)(s0+jj)*B_ + b)*H_;
    const float* wa = WqT + (size_t)mh*256;
    const float* wb = WqT + (size_t)(mh+32)*256;
    float a0=0.f, a1=0.f;
    for (int k4=0;k4<64;k4++){
      float4 h4 = *(const float4*)(hr + k4*4);
      float4 v0 = *(const float4*)(wa + k4*4);
      float4 v1 = *(const float4*)(wb + k4*4);
      a0 += dot4(h4,v0);
      a1 += dot4(h4,v1);
    }
    qL[jj][mh]    = a0 + bq[mh];
    qL[jj][mh+32] = a1 + bq[mh+32];
  }
  __syncthreads();

  const int len = slen[b];
  float sc_[8][8];
#pragma unroll
  for (int ti=0; ti<8; ti++){
    const int t = ti*256 + tid;
    const float* kr = kp + ((size_t)b*T_ + t)*M_;
    float tmp[8];
#pragma unroll
    for (int jj=0;jj<8;jj++) tmp[jj]=0.f;
#pragma unroll
    for (int u4=0; u4<4; u4++){
      float4 k0 = *(const float4*)(kr + u4*16);
      float4 k1 = *(const float4*)(kr + u4*16 + 4);
      float4 k2 = *(const float4*)(kr + u4*16 + 8);
      float4 k3 = *(const float4*)(kr + u4*16 + 12);
#pragma unroll
      for (int jj=0;jj<8;jj++){
        const float4* q4 = (const float4*)&qL[jj][u4*16];
        tmp[jj] += dot4(k0,q4[0]) + dot4(k1,q4[1]) + dot4(k2,q4[2]) + dot4(k3,q4[3]);
      }
    }
    float bias = (t<len) ? 0.f : -1e9f;
#pragma unroll
    for (int jj=0;jj<8;jj++) sc_[ti][jj] = fmaf(tmp[jj], 0.125f, bias);
  }

  float mx[8];
#pragma unroll
  for (int jj=0;jj<8;jj++){
    float m = sc_[0][jj];
#pragma unroll
    for (int ti=1;ti<8;ti++) m = fmaxf(m, sc_[ti][jj]);
#pragma unroll
    for (int off=1; off<64; off<<=1) m = fmaxf(m, __shfl_xor(m, off));
    if (lane==0) red[jj][wid] = m;
  }
  __syncthreads();
#pragma unroll
  for (int jj=0;jj<8;jj++)
    mx[jj] = fmaxf(fmaxf(red[jj][0],red[jj][1]), fmaxf(red[jj][2],red[jj][3]));
  __syncthreads();
#pragma unroll
  for (int jj=0;jj<8;jj++){
    float s = 0.f;
#pragma unroll
    for (int ti=0;ti<8;ti++){
      float e = __expf(sc_[ti][jj] - mx[jj]);
      sc_[ti][jj] = e;
      s += e;
    }
#pragma unroll
    for (int off=1; off<64; off<<=1) s += __shfl_xor(s, off);
    if (lane==0) red[jj][wid] = s;
  }
  __syncthreads();
#pragma unroll
  for (int jj=0;jj<8;jj++){
    float r = 1.f/(red[jj][0]+red[jj][1]+red[jj][2]+red[jj][3]);
    float* o = out + ((size_t)b*L_ + s0 + jj)*T_;
#pragma unroll
    for (int ti=0;ti<8;ti++) o[ti*256 + tid] = sc_[ti][jj]*r;
  }
}

// ---------------- host ----------------
extern "C" void kernel_launch(void* const* d_in, const int* in_sizes, int n_in,
                              void* d_out, int out_size, void* d_ws, size_t ws_size,
                              hipStream_t stream) {
  (void)in_sizes; (void)n_in; (void)out_size;
  const float* seq  = (const float*)d_in[0];
  const int*   slen = (const int*)  d_in[1];
  const float* Wp   = (const float*)d_in[3];
  const float* bp   = (const float*)d_in[4];
  const float* Wihe = (const float*)d_in[5];
  const float* Whhe = (const float*)d_in[6];
  const float* bihe = (const float*)d_in[7];
  const float* bhhe = (const float*)d_in[8];
  const float* Wihd = (const float*)d_in[9];
  const float* Whhd = (const float*)d_in[10];
  const float* bihd = (const float*)d_in[11];
  const float* bhhd = (const float*)d_in[12];
  const float* Wq   = (const float*)d_in[13];
  const float* bq   = (const float*)d_in[14];
  const float* Wk   = (const float*)d_in[15];
  const float* bk   = (const float*)d_in[16];
  float* out = (float*)d_out;

  char* p = (char*)d_ws;
  auto take = [&](size_t bytes)->char* {
    char* r = p; p += (bytes + 255) & ~(size_t)255; return r;
  };
  float* h2_all = (float*)take((size_t)L_*B_*H_*4);          // 8 MB
  float* kproj  = (float*)take((size_t)B_*T_*M_*4);          // 16 MB
  float* cT     = (float*)take((size_t)B_*H_*4);
  float* W_dc   = (float*)take((size_t)G4_*H_*4);            // 1 MB
  float* Wc0    = (float*)take(G4_*4);
  float* Wc1    = (float*)take(G4_*4);
  float* bc     = (float*)take(G4_*4);
  float* b_dc   = (float*)take(G4_*4);
  float* WqT    = (float*)take((size_t)M_*H_*4);
  unsigned long long* ring_e = (unsigned long long*)take((size_t)NG_*RING_*1024*8); // 512 KB
  unsigned long long* ring_d = (unsigned long long*)take((size_t)NG_*RING_*1024*8); // 512 KB

  size_t used = (size_t)(p - (char*)d_ws);
  float* h_all;
  if (ws_size >= used + (size_t)T_*B_*H_*4) {
    h_all = (float*)take((size_t)T_*B_*H_*4);                // 64 MB
  } else {
    h_all = out;  // d_out is exactly T_*B_*H_ floats; dead before attn writes
  }

  // zero tag rings each launch (tags are 1..T so 0 never matches; replay-safe)
  hipMemsetAsync(ring_e, 0, (size_t)NG_*RING_*1024*8, stream);
  hipMemsetAsync(ring_d, 0, (size_t)NG_*RING_*1024*8, stream);

  prep_wdc  <<<G4_*H_/256, 256, 0, stream>>>(Wihd, Whhd, W_dc);
  prep_small<<<68, 256, 0, stream>>>(Wp, bp, Wihe, bihe, bhhe, bihd, bhhd, Wq,
                                     Wc0, Wc1, bc, b_dc, WqT);
  enc_kernel<<<NG_*NSL_, 1024, 0, stream>>>(seq, slen, Whhe, Wc0, Wc1, bc,
                                            h_all, cT, ring_e);
  kproj_kernel<<<B_*16, 256, 0, stream>>>(h_all, slen, Wk, bk, kproj);
  dec_kernel<<<NG_*NSL_, 1024, 0, stream>>>(slen, W_dc, b_dc, h_all, cT,
                                            h2_all, ring_d);
  attn_kernel<<<B_*32, 256, 0, stream>>>(h2_all, kproj, WqT, bq, slen, out);
}

// Round 10
// 6795.800 us; speedup vs baseline: 2.9457x; 1.1265x over previous
//
#include <hip/hip_runtime.h>
#include <stdint.h>

#define B_ 32
#define T_ 2048
#define H_ 256
#define M_ 64
#define L_ 256
#define G4_ 1024     // 4*H gate rows

#define NG_ 8        // batch groups (4 batches each)
#define NSL_ 16      // hidden slices per group
#define EPT_ 16      // h elements per slice
#define RING_ 8      // ring slots (slot = t & 7); block skew <=1 so reuse distance 8 is safe

__device__ __forceinline__ float sig_fast(float x){ return 1.f/(1.f+__expf(-x)); }
__device__ __forceinline__ float tanh_fast(float x){ return 2.f/(1.f+__expf(-2.f*x)) - 1.f; }
__device__ __forceinline__ float dot4(float4 a, float4 b){
  return fmaf(a.x,b.x, fmaf(a.y,b.y, fmaf(a.z,b.z, a.w*b.w)));
}

// ---------------- prep kernels ----------------
__global__ void prep_wdc(const float* __restrict__ a, const float* __restrict__ b,
                         float* __restrict__ o){
  int i = blockIdx.x*256 + threadIdx.x;
  o[i] = a[i] + b[i];
}

__global__ void prep_small(const float* __restrict__ Wp, const float* __restrict__ bp,
                           const float* __restrict__ Wihe, const float* __restrict__ bihe,
                           const float* __restrict__ bhhe, const float* __restrict__ bihd,
                           const float* __restrict__ bhhd, const float* __restrict__ Wq,
                           float* __restrict__ Wc0, float* __restrict__ Wc1,
                           float* __restrict__ bc, float* __restrict__ bdc,
                           float* __restrict__ WqT){
  int idx = blockIdx.x*256 + threadIdx.x;
  if (idx < 16384){                 // WqT[m][k] = Wq[k][m]
    int m = idx >> 8, k = idx & 255;
    WqT[m*256 + k] = Wq[k*64 + m];
  } else if (idx < 16384 + 1024){   // fused input coeffs per gate row
    int j = idx - 16384;
    const float* wr = Wihe + j*256;
    float a0=0.f, a1=0.f, ab=0.f;
    for (int e=0;e<256;e++){
      float w = wr[e];
      a0 = fmaf(Wp[e],     w, a0);
      a1 = fmaf(Wp[256+e], w, a1);
      ab = fmaf(bp[e],     w, ab);
    }
    Wc0[j] = a0; Wc1[j] = a1;
    bc[j]  = ab + bihe[j] + bhhe[j];
    bdc[j] = bihd[j] + bhhd[j];
  }
}

// ---------------- encoder LSTM (persistent, L3/fabric ring exchange; R4 structure) ----------------
__global__ __launch_bounds__(1024) void enc_kernel(
    const float* __restrict__ seq, const int* __restrict__ slen,
    const float* __restrict__ Whh,
    const float* __restrict__ Wc0, const float* __restrict__ Wc1,
    const float* __restrict__ bc,
    float* __restrict__ h_all, float* __restrict__ cT,
    unsigned long long* __restrict__ ring)
{
  const int tid = threadIdx.x;
  const int grp = blockIdx.x & 7, slice = blockIdx.x >> 3;
  const int rp = tid >> 4, kc = tid & 15;
  const int j = ((rp >> 4) << 8) + slice*EPT_ + (rp & 15);   // gate*256 + slice*16 + elem
  float4 w0 = *(const float4*)(Whh + (size_t)j*256 +   0 + kc*4);
  float4 w1 = *(const float4*)(Whh + (size_t)j*256 +  64 + kc*4);
  float4 w2 = *(const float4*)(Whh + (size_t)j*256 + 128 + kc*4);
  float4 w3 = *(const float4*)(Whh + (size_t)j*256 + 192 + kc*4);
  float c0 = Wc0[j], c1 = Wc1[j], cbv = bc[j];

  __shared__ float hbuf[4][256];
  __shared__ float sbuf[4][2];
  __shared__ float gbuf[4][64];

  const int ub = tid >> 4, ue = tid & 15;       // updater mapping (tid<64)
  float creg = 0.f;
  int myb = 0, mylen = -1;
  if (tid < 64){ myb = grp + 8*ub; mylen = slen[myb]; }

  const int ib = tid >> 8, ik = tid & 255;      // consumer mapping: batch, elem
  unsigned long long* ringg = ring + (size_t)grp * (RING_*1024);

  for (int t = 0; t < T_; ++t){
    // ---- stage h_{t-1}: each thread polls its own 8B {tag,h} packet ----
    if (t == 0){
      hbuf[ib][ik] = 0.f;
    } else {
      const unsigned long long* pp = ringg + (size_t)((t-1) & (RING_-1))*1024 + tid;
      unsigned long long v;
      do { v = __hip_atomic_load(pp, __ATOMIC_RELAXED, __HIP_MEMORY_SCOPE_AGENT); }
      while ((unsigned)(v >> 32) != (unsigned)t);
      hbuf[ib][ik] = __uint_as_float((unsigned)v);
    }
    if (tid < 8) sbuf[tid>>1][tid&1] = seq[((size_t)(grp + 8*(tid>>1))*T_ + t)*2 + (tid&1)];
    __syncthreads();  // B1: hbuf/sbuf ready

    // ---- compute: one gate row per thread, K split over 16 lanes ----
#pragma unroll
    for (int i = 0; i < 4; ++i){
      float4 h0 = *(const float4*)&hbuf[i][       kc*4];
      float4 h1 = *(const float4*)&hbuf[i][ 64 + kc*4];
      float4 h2 = *(const float4*)&hbuf[i][128 + kc*4];
      float4 h3 = *(const float4*)&hbuf[i][192 + kc*4];
      float a = dot4(w0,h0) + dot4(w1,h1) + dot4(w2,h2) + dot4(w3,h3);
#pragma unroll
      for (int off = 1; off < 16; off <<= 1) a += __shfl_xor(a, off);
      if (kc == 0)
        gbuf[i][rp] = fmaf(sbuf[i][0], c0, fmaf(sbuf[i][1], c1, a + cbv));
    }
    __syncthreads();  // B2: gbuf ready

    // ---- update + publish-first (tid<64: 4 batches x 16 elems) ----
    if (tid < 64){
      float gi = gbuf[ub][      ue];
      float gf = gbuf[ub][16 + ue];
      float gg = gbuf[ub][32 + ue];
      float go = gbuf[ub][48 + ue];
      creg = sig_fast(gf)*creg + sig_fast(gi)*tanh_fast(gg);
      float h = sig_fast(go)*tanh_fast(creg);
      unsigned long long pk = ((unsigned long long)(unsigned)(t+1) << 32)
                            | (unsigned long long)__float_as_uint(h);
      // critical-path packet FIRST, off-path stores after
      __hip_atomic_store(ringg + (size_t)(t & (RING_-1))*1024 + ub*256 + slice*EPT_ + ue,
                         pk, __ATOMIC_RELAXED, __HIP_MEMORY_SCOPE_AGENT);
      h_all[((size_t)t*B_ + myb)*H_ + slice*EPT_ + ue] = h;
      if (t == mylen - 1) cT[myb*H_ + slice*EPT_ + ue] = creg;
    }
    // next-iter staging rewrites hbuf only after B1-crossing; safe without B3
  }
}

// ---------------- decoder LSTM (x == h, folded weights) ----------------
__global__ __launch_bounds__(1024) void dec_kernel(
    const int* __restrict__ slen,
    const float* __restrict__ Wdc, const float* __restrict__ bdc,
    const float* __restrict__ h_all, const float* __restrict__ cT,
    float* __restrict__ h2_all, unsigned long long* __restrict__ ring)
{
  const int tid = threadIdx.x;
  const int grp = blockIdx.x & 7, slice = blockIdx.x >> 3;
  const int rp = tid >> 4, kc = tid & 15;
  const int j = ((rp >> 4) << 8) + slice*EPT_ + (rp & 15);
  float4 w0 = *(const float4*)(Wdc + (size_t)j*256 +   0 + kc*4);
  float4 w1 = *(const float4*)(Wdc + (size_t)j*256 +  64 + kc*4);
  float4 w2 = *(const float4*)(Wdc + (size_t)j*256 + 128 + kc*4);
  float4 w3 = *(const float4*)(Wdc + (size_t)j*256 + 192 + kc*4);
  float cbv = bdc[j];

  __shared__ float hbuf[4][256];
  __shared__ float gbuf[4][64];

  const int ub = tid >> 4, ue = tid & 15;
  float creg = 0.f; int myb = 0;
  if (tid < 64){ myb = grp + 8*ub; creg = cT[myb*H_ + slice*EPT_ + ue]; }

  const int tb = tid >> 7, kp = tid & 127;      // s==0 bulk-stage mapping (tid<512)
  const int stage_b = grp + 8*tb;
  int stage_len = 1;
  if (tid < 512) stage_len = slen[stage_b];

  const int ib = tid >> 8, ik = tid & 255;
  unsigned long long* ringg = ring + (size_t)grp * (RING_*1024);

  for (int s = 0; s < L_; ++s){
    if (s == 0){
      if (tid < 512)   // h_all fully written by completed enc kernel: plain loads OK
        *(float2*)&hbuf[tb][kp*2] =
            *(const float2*)(h_all + ((size_t)(stage_len-1)*B_ + stage_b)*H_ + kp*2);
    } else {
      const unsigned long long* pp = ringg + (size_t)((s-1) & (RING_-1))*1024 + tid;
      unsigned long long v;
      do { v = __hip_atomic_load(pp, __ATOMIC_RELAXED, __HIP_MEMORY_SCOPE_AGENT); }
      while ((unsigned)(v >> 32) != (unsigned)s);
      hbuf[ib][ik] = __uint_as_float((unsigned)v);
    }
    __syncthreads();  // B1

#pragma unroll
    for (int i = 0; i < 4; ++i){
      float4 h0 = *(const float4*)&hbuf[i][       kc*4];
      float4 h1 = *(const float4*)&hbuf[i][ 64 + kc*4];
      float4 h2 = *(const float4*)&hbuf[i][128 + kc*4];
      float4 h3 = *(const float4*)&hbuf[i][192 + kc*4];
      float a = dot4(w0,h0) + dot4(w1,h1) + dot4(w2,h2) + dot4(w3,h3);
#pragma unroll
      for (int off = 1; off < 16; off <<= 1) a += __shfl_xor(a, off);
      if (kc == 0) gbuf[i][rp] = a + cbv;
    }
    __syncthreads();  // B2

    if (tid < 64){
      float gi = gbuf[ub][      ue];
      float gf = gbuf[ub][16 + ue];
      float gg = gbuf[ub][32 + ue];
      float go = gbuf[ub][48 + ue];
      creg = sig_fast(gf)*creg + sig_fast(gi)*tanh_fast(gg);
      float h = sig_fast(go)*tanh_fast(creg);
      unsigned long long pk = ((unsigned long long)(unsigned)(s+1) << 32)
                            | (unsigned long long)__float_as_uint(h);
      __hip_atomic_store(ringg + (size_t)(s & (RING_-1))*1024 + ub*256 + slice*EPT_ + ue,
                         pk, __ATOMIC_RELAXED, __HIP_MEMORY_SCOPE_AGENT);
      h2_all[((size_t)s*B_ + myb)*H_ + slice*EPT_ + ue] = h;
    }
  }
}

// ---------------- kproj = masked(enc) @ Wk + bk ----------------
__global__ __launch_bounds__(256) void kproj_kernel(
    const float* __restrict__ h_all, const int* __restrict__ slen,
    const float* __restrict__ Wk, const float* __restrict__ bk,
    float* __restrict__ kp)
{
  __shared__ float wk[256*64];
  const int tid = threadIdx.x;
  const int b = blockIdx.x >> 4, tc = blockIdx.x & 15;
  const int t0 = tc*128;
#pragma unroll
  for (int i=0;i<16;i++){
    int idx = tid + i*256;
    *(float4*)(&wk[idx*4]) = *(const float4*)(Wk + idx*4);
  }
  __syncthreads();
  const int tp = tid>>2, mc = (tid&3)*16;
  const int ta = t0 + tp*2, tb = ta+1;
  const int len = slen[b];
  const bool va = ta < len, vb = tb < len;
  const float* ha = h_all + ((size_t)ta*B_ + b)*H_;
  const float* hb = h_all + ((size_t)tb*B_ + b)*H_;
  float4 A[4], Bv[4];
#pragma unroll
  for (int u=0;u<4;u++){ A[u].x=A[u].y=A[u].z=A[u].w=0.f; Bv[u]=A[u]; }

  for (int k4=0;k4<64;k4++){
    float xa[4], xb_[4];
    if (va){ float4 v = *(const float4*)(ha + k4*4); xa[0]=v.x; xa[1]=v.y; xa[2]=v.z; xa[3]=v.w; }
    else   { xa[0]=xa[1]=xa[2]=xa[3]=0.f; }
    if (vb){ float4 v = *(const float4*)(hb + k4*4); xb_[0]=v.x; xb_[1]=v.y; xb_[2]=v.z; xb_[3]=v.w; }
    else   { xb_[0]=xb_[1]=xb_[2]=xb_[3]=0.f; }
#pragma unroll
    for (int jj=0;jj<4;jj++){
      const float* wr = &wk[(k4*4+jj)*64 + mc];
#pragma unroll
      for (int u=0;u<4;u++){
        float4 wv = *(const float4*)(wr + u*4);
        A[u].x  = fmaf(xa[jj],wv.x,A[u].x);  A[u].y  = fmaf(xa[jj],wv.y,A[u].y);
        A[u].z  = fmaf(xa[jj],wv.z,A[u].z);  A[u].w  = fmaf(xa[jj],wv.w,A[u].w);
        Bv[u].x = fmaf(xb_[jj],wv.x,Bv[u].x); Bv[u].y = fmaf(xb_[jj],wv.y,Bv[u].y);
        Bv[u].z = fmaf(xb_[jj],wv.z,Bv[u].z); Bv[u].w = fmaf(xb_[jj],wv.w,Bv[u].w);
      }
    }
  }
#pragma unroll
  for (int u=0;u<4;u++){
    float4 bkv = *(const float4*)(bk + mc + u*4);
    float4 ra, rb;
    ra.x = va ? A[u].x+bkv.x : bkv.x;  ra.y = va ? A[u].y+bkv.y : bkv.y;
    ra.z = va ? A[u].z+bkv.z : bkv.z;  ra.w = va ? A[u].w+bkv.w : bkv.w;
    rb.x = vb ? Bv[u].x+bkv.x : bkv.x; rb.y = vb ? Bv[u].y+bkv.y : bkv.y;
    rb.z = vb ? Bv[u].z+bkv.z : bkv.z; rb.w = vb ? Bv[u].w+bkv.w : bkv.w;
    *(float4*)(kp + ((size_t)b*T_+ta)*M_ + mc + u*4) = ra;
    *(float4*)(kp + ((size_t)b*T_+tb)*M_ + mc + u*4) = rb;
  }
}

// ---------------- attention ----------------
__global__ __launch_bounds__(256) void attn_kernel(
    const float* __restrict__ h2_all, const float* __restrict__ kp,
    const float* __restrict__ WqT, const float* __restrict__ bq,
    const int* __restrict__ slen, float* __restrict__ out)
{
  const int tid = threadIdx.x;
  const int b = blockIdx.x >> 5, scg = blockIdx.x & 31;
  const int s0 = scg*8;
  __shared__ float qL[8][64];
  __shared__ float red[8][4];
  const int wid = tid>>6, lane = tid&63;

  { // q = h2 @ Wq + bq
    const int jj = tid>>5, mh = tid&31;
    const float* hr = h2_all + ((size_t)(s0+jj)*B_ + b)*H_;
    const float* wa = WqT + (size_t)mh*256;
    const float* wb = WqT + (size_t)(mh+32)*256;
    float a0=0.f, a1=0.f;
    for (int k4=0;k4<64;k4++){
      float4 h4 = *(const float4*)(hr + k4*4);
      float4 v0 = *(const float4*)(wa + k4*4);
      float4 v1 = *(const float4*)(wb + k4*4);
      a0 += dot4(h4,v0);
      a1 += dot4(h4,v1);
    }
    qL[jj][mh]    = a0 + bq[mh];
    qL[jj][mh+32] = a1 + bq[mh+32];
  }
  __syncthreads();

  const int len = slen[b];
  float sc_[8][8];
#pragma unroll
  for (int ti=0; ti<8; ti++){
    const int t = ti*256 + tid;
    const float* kr = kp + ((size_t)b*T_ + t)*M_;
    float tmp[8];
#pragma unroll
    for (int jj=0;jj<8;jj++) tmp[jj]=0.f;
#pragma unroll
    for (int u4=0; u4<4; u4++){
      float4 k0 = *(const float4*)(kr + u4*16);
      float4 k1 = *(const float4*)(kr + u4*16 + 4);
      float4 k2 = *(const float4*)(kr + u4*16 + 8);
      float4 k3 = *(const float4*)(kr + u4*16 + 12);
#pragma unroll
      for (int jj=0;jj<8;jj++){
        const float4* q4 = (const float4*)&qL[jj][u4*16];
        tmp[jj] += dot4(k0,q4[0]) + dot4(k1,q4[1]) + dot4(k2,q4[2]) + dot4(k3,q4[3]);
      }
    }
    float bias = (t<len) ? 0.f : -1e9f;
#pragma unroll
    for (int jj=0;jj<8;jj++) sc_[ti][jj] = fmaf(tmp[jj], 0.125f, bias);
  }

  float mx[8];
#pragma unroll
  for (int jj=0;jj<8;jj++){
    float m = sc_[0][jj];
#pragma unroll
    for (int ti=1;ti<8;ti++) m = fmaxf(m, sc_[ti][jj]);
#pragma unroll
    for (int off=1; off<64; off<<=1) m = fmaxf(m, __shfl_xor(m, off));
    if (lane==0) red[jj][wid] = m;
  }
  __syncthreads();
#pragma unroll
  for (int jj=0;jj<8;jj++)
    mx[jj] = fmaxf(fmaxf(red[jj][0],red[jj][1]), fmaxf(red[jj][2],red[jj][3]));
  __syncthreads();
#pragma unroll
  for (int jj=0;jj<8;jj++){
    float s = 0.f;
#pragma unroll
    for (int ti=0;ti<8;ti++){
      float e = __expf(sc_[ti][jj] - mx[jj]);
      sc_[ti][jj] = e;
      s += e;
    }
#pragma unroll
    for (int off=1; off<64; off<<=1) s += __shfl_xor(s, off);
    if (lane==0) red[jj][wid] = s;
  }
  __syncthreads();
#pragma unroll
  for (int jj=0;jj<8;jj++){
    float r = 1.f/(red[jj][0]+red[jj][1]+red[jj][2]+red[jj][3]);
    float* o = out + ((size_t)b*L_ + s0 + jj)*T_;
#pragma unroll
    for (int ti=0;ti<8;ti++) o[ti*256 + tid] = sc_[ti][jj]*r;
  }
}

// ---------------- host ----------------
extern "C" void kernel_launch(void* const* d_in, const int* in_sizes, int n_in,
                              void* d_out, int out_size, void* d_ws, size_t ws_size,
                              hipStream_t stream) {
  (void)in_sizes; (void)n_in; (void)out_size;
  const float* seq  = (const float*)d_in[0];
  const int*   slen = (const int*)  d_in[1];
  const float* Wp   = (const float*)d_in[3];
  const float* bp   = (const float*)d_in[4];
  const float* Wihe = (const float*)d_in[5];
  const float* Whhe = (const float*)d_in[6];
  const float* bihe = (const float*)d_in[7];
  const float* bhhe = (const float*)d_in[8];
  const float* Wihd = (const float*)d_in[9];
  const float* Whhd = (const float*)d_in[10];
  const float* bihd = (const float*)d_in[11];
  const float* bhhd = (const float*)d_in[12];
  const float* Wq   = (const float*)d_in[13];
  const float* bq   = (const float*)d_in[14];
  const float* Wk   = (const float*)d_in[15];
  const float* bk   = (const float*)d_in[16];
  float* out = (float*)d_out;

  char* p = (char*)d_ws;
  auto take = [&](size_t bytes)->char* {
    char* r = p; p += (bytes + 255) & ~(size_t)255; return r;
  };
  float* h2_all = (float*)take((size_t)L_*B_*H_*4);          // 8 MB
  float* kproj  = (float*)take((size_t)B_*T_*M_*4);          // 16 MB
  float* cT     = (float*)take((size_t)B_*H_*4);
  float* W_dc   = (float*)take((size_t)G4_*H_*4);            // 1 MB
  float* Wc0    = (float*)take(G4_*4);
  float* Wc1    = (float*)take(G4_*4);
  float* bc     = (float*)take(G4_*4);
  float* b_dc   = (float*)take(G4_*4);
  float* WqT    = (float*)take((size_t)M_*H_*4);
  unsigned long long* ring_e = (unsigned long long*)take((size_t)NG_*RING_*1024*8); // 512 KB
  unsigned long long* ring_d = (unsigned long long*)take((size_t)NG_*RING_*1024*8); // 512 KB

  size_t used = (size_t)(p - (char*)d_ws);
  float* h_all;
  if (ws_size >= used + (size_t)T_*B_*H_*4) {
    h_all = (float*)take((size_t)T_*B_*H_*4);                // 64 MB
  } else {
    h_all = out;  // d_out is exactly T_*B_*H_ floats; dead before attn writes
  }

  // zero the tag rings (tags are 1..T so 0 never matches); re-zeroed every replay
  hipMemsetAsync(ring_e, 0, (size_t)NG_*RING_*1024*8, stream);
  hipMemsetAsync(ring_d, 0, (size_t)NG_*RING_*1024*8, stream);

  prep_wdc  <<<G4_*H_/256, 256, 0, stream>>>(Wihd, Whhd, W_dc);
  prep_small<<<68, 256, 0, stream>>>(Wp, bp, Wihe, bihe, bhhe, bihd, bhhd, Wq,
                                     Wc0, Wc1, bc, b_dc, WqT);
  enc_kernel<<<NG_*NSL_, 1024, 0, stream>>>(seq, slen, Whhe, Wc0, Wc1, bc,
                                            h_all, cT, ring_e);
  kproj_kernel<<<B_*16, 256, 0, stream>>>(h_all, slen, Wk, bk, kproj);
  dec_kernel<<<NG_*NSL_, 1024, 0, stream>>>(slen, W_dc, b_dc, h_all, cT,
                                            h2_all, ring_d);
  attn_kernel<<<B_*32, 256, 0, stream>>>(h2_all, kproj, WqT, bq, slen, out);
}

// Round 11
// 6752.334 us; speedup vs baseline: 2.9647x; 1.0064x over previous
//
#include <hip/hip_runtime.h>
#include <stdint.h>

#define B_ 32
#define T_ 2048
#define H_ 256
#define M_ 64
#define L_ 256
#define G4_ 1024     // 4*H gate rows

#define NG_ 8        // batch groups (4 batches each)
#define NSL_ 16      // hidden slices per group
#define EPT_ 16      // h elements per slice
#define RING_ 8      // ring slots (slot = t & 7); block skew <=1 so reuse distance 8 is safe
#define NDEC_ 128    // dec blocks in fused dec+kproj launch

__device__ __forceinline__ float sig_fast(float x){ return 1.f/(1.f+__expf(-x)); }
__device__ __forceinline__ float tanh_fast(float x){ return 2.f/(1.f+__expf(-2.f*x)) - 1.f; }
__device__ __forceinline__ float dot4(float4 a, float4 b){
  return fmaf(a.x,b.x, fmaf(a.y,b.y, fmaf(a.z,b.z, a.w*b.w)));
}

// ---------------- merged prep kernel ----------------
__global__ void prep_all(const float* __restrict__ Wihd, const float* __restrict__ Whhd,
                         float* __restrict__ Wdc,
                         const float* __restrict__ Wp, const float* __restrict__ bp,
                         const float* __restrict__ Wihe, const float* __restrict__ bihe,
                         const float* __restrict__ bhhe, const float* __restrict__ bihd,
                         const float* __restrict__ bhhd, const float* __restrict__ Wq,
                         float* __restrict__ Wc0, float* __restrict__ Wc1,
                         float* __restrict__ bc, float* __restrict__ bdc,
                         float* __restrict__ WqT){
  const int bid = blockIdx.x;
  if (bid < 1024){                      // decoder weight fold: Wih_d + Whh_d
    int i = bid*256 + threadIdx.x;
    Wdc[i] = Wihd[i] + Whhd[i];
    return;
  }
  int idx = (bid - 1024)*256 + threadIdx.x;
  if (idx < 16384){                     // WqT[m][k] = Wq[k][m]
    int m = idx >> 8, k = idx & 255;
    WqT[m*256 + k] = Wq[k*64 + m];
  } else if (idx < 16384 + 1024){       // fused input coeffs per gate row
    int j = idx - 16384;
    const float* wr = Wihe + j*256;
    float a0=0.f, a1=0.f, ab=0.f;
    for (int e=0;e<256;e++){
      float w = wr[e];
      a0 = fmaf(Wp[e],     w, a0);
      a1 = fmaf(Wp[256+e], w, a1);
      ab = fmaf(bp[e],     w, ab);
    }
    Wc0[j] = a0; Wc1[j] = a1;
    bc[j]  = ab + bihe[j] + bhhe[j];
    bdc[j] = bihd[j] + bhhd[j];
  }
}

// ---------------- encoder LSTM (persistent; R4 fused-packet ring — best known) ----------------
__global__ __launch_bounds__(1024) void enc_kernel(
    const float* __restrict__ seq, const int* __restrict__ slen,
    const float* __restrict__ Whh,
    const float* __restrict__ Wc0, const float* __restrict__ Wc1,
    const float* __restrict__ bc,
    float* __restrict__ h_all, float* __restrict__ cT,
    unsigned long long* __restrict__ ring)
{
  const int tid = threadIdx.x;
  const int grp = blockIdx.x & 7, slice = blockIdx.x >> 3;
  const int rp = tid >> 4, kc = tid & 15;
  const int j = ((rp >> 4) << 8) + slice*EPT_ + (rp & 15);   // gate*256 + slice*16 + elem
  float4 w0 = *(const float4*)(Whh + (size_t)j*256 +   0 + kc*4);
  float4 w1 = *(const float4*)(Whh + (size_t)j*256 +  64 + kc*4);
  float4 w2 = *(const float4*)(Whh + (size_t)j*256 + 128 + kc*4);
  float4 w3 = *(const float4*)(Whh + (size_t)j*256 + 192 + kc*4);
  float c0 = Wc0[j], c1 = Wc1[j], cbv = bc[j];

  __shared__ float hbuf[4][256];
  __shared__ float sbuf[4][2];
  __shared__ float gbuf[4][64];

  const int ub = tid >> 4, ue = tid & 15;       // updater mapping (tid<64)
  float creg = 0.f;
  int myb = 0, mylen = -1;
  if (tid < 64){ myb = grp + 8*ub; mylen = slen[myb]; }

  const int ib = tid >> 8, ik = tid & 255;      // consumer mapping: batch, elem
  unsigned long long* ringg = ring + (size_t)grp * (RING_*1024);

  for (int t = 0; t < T_; ++t){
    // ---- stage h_{t-1}: each thread polls its own 8B {tag,h} packet ----
    if (t == 0){
      hbuf[ib][ik] = 0.f;
    } else {
      const unsigned long long* pp = ringg + (size_t)((t-1) & (RING_-1))*1024 + tid;
      unsigned long long v;
      do { v = __hip_atomic_load(pp, __ATOMIC_RELAXED, __HIP_MEMORY_SCOPE_AGENT); }
      while ((unsigned)(v >> 32) != (unsigned)t);
      hbuf[ib][ik] = __uint_as_float((unsigned)v);
    }
    if (tid < 8) sbuf[tid>>1][tid&1] = seq[((size_t)(grp + 8*(tid>>1))*T_ + t)*2 + (tid&1)];
    __syncthreads();  // B1: hbuf/sbuf ready

    // ---- compute: one gate row per thread, K split over 16 lanes ----
#pragma unroll
    for (int i = 0; i < 4; ++i){
      float4 h0 = *(const float4*)&hbuf[i][       kc*4];
      float4 h1 = *(const float4*)&hbuf[i][ 64 + kc*4];
      float4 h2 = *(const float4*)&hbuf[i][128 + kc*4];
      float4 h3 = *(const float4*)&hbuf[i][192 + kc*4];
      float a = dot4(w0,h0) + dot4(w1,h1) + dot4(w2,h2) + dot4(w3,h3);
#pragma unroll
      for (int off = 1; off < 16; off <<= 1) a += __shfl_xor(a, off);
      if (kc == 0)
        gbuf[i][rp] = fmaf(sbuf[i][0], c0, fmaf(sbuf[i][1], c1, a + cbv));
    }
    __syncthreads();  // B2: gbuf ready

    // ---- update + publish (tid<64: 4 batches x 16 elems) ----
    if (tid < 64){
      float gi = gbuf[ub][      ue];
      float gf = gbuf[ub][16 + ue];
      float gg = gbuf[ub][32 + ue];
      float go = gbuf[ub][48 + ue];
      creg = sig_fast(gf)*creg + sig_fast(gi)*tanh_fast(gg);
      float h = sig_fast(go)*tanh_fast(creg);
      unsigned long long pk = ((unsigned long long)(unsigned)(t+1) << 32)
                            | (unsigned long long)__float_as_uint(h);
      __hip_atomic_store(ringg + (size_t)(t & (RING_-1))*1024 + ub*256 + slice*EPT_ + ue,
                         pk, __ATOMIC_RELAXED, __HIP_MEMORY_SCOPE_AGENT);
      h_all[((size_t)t*B_ + myb)*H_ + slice*EPT_ + ue] = h;
      if (t == mylen - 1) cT[myb*H_ + slice*EPT_ + ue] = creg;
    }
    // next-iter staging rewrites hbuf only after B1-crossing; safe without B3
  }
}

// -------- fused decoder LSTM + kproj (mutually independent; share one launch) --------
__global__ __launch_bounds__(1024) void dec_kproj_kernel(
    const int* __restrict__ slen,
    const float* __restrict__ Wdc, const float* __restrict__ bdc,
    const float* __restrict__ h_all, const float* __restrict__ cT,
    float* __restrict__ h2_all, unsigned long long* __restrict__ ring,
    const float* __restrict__ Wk, const float* __restrict__ bk,
    float* __restrict__ kp)
{
  const int bid = blockIdx.x;
  const int tid = threadIdx.x;

  __shared__ float hbuf[4][256];
  __shared__ float gbuf[4][64];
  __shared__ float wk[256*64];   // kproj staging (64 KB; sum with dec LDS still < 160 KB)

  if (bid < NDEC_){
    // ---------------- dec path (identical to proven R10 dec body) ----------------
    const int grp = bid & 7, slice = bid >> 3;
    const int rp = tid >> 4, kc = tid & 15;
    const int j = ((rp >> 4) << 8) + slice*EPT_ + (rp & 15);
    float4 w0 = *(const float4*)(Wdc + (size_t)j*256 +   0 + kc*4);
    float4 w1 = *(const float4*)(Wdc + (size_t)j*256 +  64 + kc*4);
    float4 w2 = *(const float4*)(Wdc + (size_t)j*256 + 128 + kc*4);
    float4 w3 = *(const float4*)(Wdc + (size_t)j*256 + 192 + kc*4);
    float cbv = bdc[j];

    const int ub = tid >> 4, ue = tid & 15;
    float creg = 0.f; int myb = 0;
    if (tid < 64){ myb = grp + 8*ub; creg = cT[myb*H_ + slice*EPT_ + ue]; }

    const int tb = tid >> 7, kpp = tid & 127;   // s==0 bulk-stage mapping (tid<512)
    const int stage_b = grp + 8*tb;
    int stage_len = 1;
    if (tid < 512) stage_len = slen[stage_b];

    const int ib = tid >> 8, ik = tid & 255;
    unsigned long long* ringg = ring + (size_t)grp * (RING_*1024);

    for (int s = 0; s < L_; ++s){
      if (s == 0){
        if (tid < 512)   // h_all fully written by completed enc kernel: plain loads OK
          *(float2*)&hbuf[tb][kpp*2] =
              *(const float2*)(h_all + ((size_t)(stage_len-1)*B_ + stage_b)*H_ + kpp*2);
      } else {
        const unsigned long long* pp = ringg + (size_t)((s-1) & (RING_-1))*1024 + tid;
        unsigned long long v;
        do { v = __hip_atomic_load(pp, __ATOMIC_RELAXED, __HIP_MEMORY_SCOPE_AGENT); }
        while ((unsigned)(v >> 32) != (unsigned)s);
        hbuf[ib][ik] = __uint_as_float((unsigned)v);
      }
      __syncthreads();  // B1

#pragma unroll
      for (int i = 0; i < 4; ++i){
        float4 h0 = *(const float4*)&hbuf[i][       kc*4];
        float4 h1 = *(const float4*)&hbuf[i][ 64 + kc*4];
        float4 h2 = *(const float4*)&hbuf[i][128 + kc*4];
        float4 h3 = *(const float4*)&hbuf[i][192 + kc*4];
        float a = dot4(w0,h0) + dot4(w1,h1) + dot4(w2,h2) + dot4(w3,h3);
#pragma unroll
        for (int off = 1; off < 16; off <<= 1) a += __shfl_xor(a, off);
        if (kc == 0) gbuf[i][rp] = a + cbv;
      }
      __syncthreads();  // B2

      if (tid < 64){
        float gi = gbuf[ub][      ue];
        float gf = gbuf[ub][16 + ue];
        float gg = gbuf[ub][32 + ue];
        float go = gbuf[ub][48 + ue];
        creg = sig_fast(gf)*creg + sig_fast(gi)*tanh_fast(gg);
        float h = sig_fast(go)*tanh_fast(creg);
        unsigned long long pk = ((unsigned long long)(unsigned)(s+1) << 32)
                              | (unsigned long long)__float_as_uint(h);
        __hip_atomic_store(ringg + (size_t)(s & (RING_-1))*1024 + ub*256 + slice*EPT_ + ue,
                           pk, __ATOMIC_RELAXED, __HIP_MEMORY_SCOPE_AGENT);
        h2_all[((size_t)s*B_ + myb)*H_ + slice*EPT_ + ue] = h;
      }
    }
  } else {
    // ---------------- kproj path: one block per batch, 16 t-chunks via 4 iters x 4 quarters ----------------
    const int b = bid - NDEC_;
#pragma unroll
    for (int i=0;i<4;i++){
      int idx = tid + i*1024;
      *(float4*)(&wk[idx*4]) = *(const float4*)(Wk + idx*4);
    }
    __syncthreads();
    const int lane = tid & 255, q = tid >> 8;
    const int tp = lane >> 2, mc = (lane & 3)*16;
    const int len = slen[b];

    for (int it = 0; it < 4; ++it){
      const int t0 = (it*4 + q)*128;
      const int ta = t0 + tp*2, tb2 = ta+1;
      const bool va = ta < len, vb = tb2 < len;
      const float* ha = h_all + ((size_t)ta*B_ + b)*H_;
      const float* hb = h_all + ((size_t)tb2*B_ + b)*H_;
      float4 A[4], Bv[4];
#pragma unroll
      for (int u=0;u<4;u++){ A[u].x=A[u].y=A[u].z=A[u].w=0.f; Bv[u]=A[u]; }

      for (int k4=0;k4<64;k4++){
        float xa[4], xb_[4];
        if (va){ float4 v = *(const float4*)(ha + k4*4); xa[0]=v.x; xa[1]=v.y; xa[2]=v.z; xa[3]=v.w; }
        else   { xa[0]=xa[1]=xa[2]=xa[3]=0.f; }
        if (vb){ float4 v = *(const float4*)(hb + k4*4); xb_[0]=v.x; xb_[1]=v.y; xb_[2]=v.z; xb_[3]=v.w; }
        else   { xb_[0]=xb_[1]=xb_[2]=xb_[3]=0.f; }
#pragma unroll
        for (int jj=0;jj<4;jj++){
          const float* wr = &wk[(k4*4+jj)*64 + mc];
#pragma unroll
          for (int u=0;u<4;u++){
            float4 wv = *(const float4*)(wr + u*4);
            A[u].x  = fmaf(xa[jj],wv.x,A[u].x);  A[u].y  = fmaf(xa[jj],wv.y,A[u].y);
            A[u].z  = fmaf(xa[jj],wv.z,A[u].z);  A[u].w  = fmaf(xa[jj],wv.w,A[u].w);
            Bv[u].x = fmaf(xb_[jj],wv.x,Bv[u].x); Bv[u].y = fmaf(xb_[jj],wv.y,Bv[u].y);
            Bv[u].z = fmaf(xb_[jj],wv.z,Bv[u].z); Bv[u].w = fmaf(xb_[jj],wv.w,Bv[u].w);
          }
        }
      }
#pragma unroll
      for (int u=0;u<4;u++){
        float4 bkv = *(const float4*)(bk + mc + u*4);
        float4 ra, rb;
        ra.x = va ? A[u].x+bkv.x : bkv.x;  ra.y = va ? A[u].y+bkv.y : bkv.y;
        ra.z = va ? A[u].z+bkv.z : bkv.z;  ra.w = va ? A[u].w+bkv.w : bkv.w;
        rb.x = vb ? Bv[u].x+bkv.x : bkv.x; rb.y = vb ? Bv[u].y+bkv.y : bkv.y;
        rb.z = vb ? Bv[u].z+bkv.z : bkv.z; rb.w = vb ? Bv[u].w+bkv.w : bkv.w;
        *(float4*)(kp + ((size_t)b*T_+ta)*M_ + mc + u*4) = ra;
        *(float4*)(kp + ((size_t)b*T_+tb2)*M_ + mc + u*4) = rb;
      }
    }
  }
}

// ---------------- attention ----------------
__global__ __launch_bounds__(256) void attn_kernel(
    const float* __restrict__ h2_all, const float* __restrict__ kp,
    const float* __restrict__ WqT, const float* __restrict__ bq,
    const int* __restrict__ slen, float* __restrict__ out)
{
  const int tid = threadIdx.x;
  const int b = blockIdx.x >> 5, scg = blockIdx.x & 31;
  const int s0 = scg*8;
  __shared__ float qL[8][64];
  __shared__ float red[8][4];
  const int wid = tid>>6, lane = tid&63;

  { // q = h2 @ Wq + bq
    const int jj = tid>>5, mh = tid&31;
    const float* hr = h2_all + ((size_t)(s0+jj)*B_ + b)*H_;
    const float* wa = WqT + (size_t)mh*256;
    const float* wb = WqT + (size_t)(mh+32)*256;
    float a0=0.f, a1=0.f;
    for (int k4=0;k4<64;k4++){
      float4 h4 = *(const float4*)(hr + k4*4);
      float4 v0 = *(const float4*)(wa + k4*4);
      float4 v1 = *(const float4*)(wb + k4*4);
      a0 += dot4(h4,v0);
      a1 += dot4(h4,v1);
    }
    qL[jj][mh]    = a0 + bq[mh];
    qL[jj][mh+32] = a1 + bq[mh+32];
  }
  __syncthreads();

  const int len = slen[b];
  float sc_[8][8];
#pragma unroll
  for (int ti=0; ti<8; ti++){
    const int t = ti*256 + tid;
    const float* kr = kp + ((size_t)b*T_ + t)*M_;
    float tmp[8];
#pragma unroll
    for (int jj=0;jj<8;jj++) tmp[jj]=0.f;
#pragma unroll
    for (int u4=0; u4<4; u4++){
      float4 k0 = *(const float4*)(kr + u4*16);
      float4 k1 = *(const float4*)(kr + u4*16 + 4);
      float4 k2 = *(const float4*)(kr + u4*16 + 8);
      float4 k3 = *(const float4*)(kr + u4*16 + 12);
#pragma unroll
      for (int jj=0;jj<8;jj++){
        const float4* q4 = (const float4*)&qL[jj][u4*16];
        tmp[jj] += dot4(k0,q4[0]) + dot4(k1,q4[1]) + dot4(k2,q4[2]) + dot4(k3,q4[3]);
      }
    }
    float bias = (t<len) ? 0.f : -1e9f;
#pragma unroll
    for (int jj=0;jj<8;jj++) sc_[ti][jj] = fmaf(tmp[jj], 0.125f, bias);
  }

  float mx[8];
#pragma unroll
  for (int jj=0;jj<8;jj++){
    float m = sc_[0][jj];
#pragma unroll
    for (int ti=1;ti<8;ti++) m = fmaxf(m, sc_[ti][jj]);
#pragma unroll
    for (int off=1; off<64; off<<=1) m = fmaxf(m, __shfl_xor(m, off));
    if (lane==0) red[jj][wid] = m;
  }
  __syncthreads();
#pragma unroll
  for (int jj=0;jj<8;jj++)
    mx[jj] = fmaxf(fmaxf(red[jj][0],red[jj][1]), fmaxf(red[jj][2],red[jj][3]));
  __syncthreads();
#pragma unroll
  for (int jj=0;jj<8;jj++){
    float s = 0.f;
#pragma unroll
    for (int ti=0;ti<8;ti++){
      float e = __expf(sc_[ti][jj] - mx[jj]);
      sc_[ti][jj] = e;
      s += e;
    }
#pragma unroll
    for (int off=1; off<64; off<<=1) s += __shfl_xor(s, off);
    if (lane==0) red[jj][wid] = s;
  }
  __syncthreads();
#pragma unroll
  for (int jj=0;jj<8;jj++){
    float r = 1.f/(red[jj][0]+red[jj][1]+red[jj][2]+red[jj][3]);
    float* o = out + ((size_t)b*L_ + s0 + jj)*T_;
#pragma unroll
    for (int ti=0;ti<8;ti++) o[ti*256 + tid] = sc_[ti][jj]*r;
  }
}

// ---------------- host ----------------
extern "C" void kernel_launch(void* const* d_in, const int* in_sizes, int n_in,
                              void* d_out, int out_size, void* d_ws, size_t ws_size,
                              hipStream_t stream) {
  (void)in_sizes; (void)n_in; (void)out_size;
  const float* seq  = (const float*)d_in[0];
  const int*   slen = (const int*)  d_in[1];
  const float* Wp   = (const float*)d_in[3];
  const float* bp   = (const float*)d_in[4];
  const float* Wihe = (const float*)d_in[5];
  const float* Whhe = (const float*)d_in[6];
  const float* bihe = (const float*)d_in[7];
  const float* bhhe = (const float*)d_in[8];
  const float* Wihd = (const float*)d_in[9];
  const float* Whhd = (const float*)d_in[10];
  const float* bihd = (const float*)d_in[11];
  const float* bhhd = (const float*)d_in[12];
  const float* Wq   = (const float*)d_in[13];
  const float* bq   = (const float*)d_in[14];
  const float* Wk   = (const float*)d_in[15];
  const float* bk   = (const float*)d_in[16];
  float* out = (float*)d_out;

  char* p = (char*)d_ws;
  auto take = [&](size_t bytes)->char* {
    char* r = p; p += (bytes + 255) & ~(size_t)255; return r;
  };
  float* h2_all = (float*)take((size_t)L_*B_*H_*4);          // 8 MB
  float* kproj  = (float*)take((size_t)B_*T_*M_*4);          // 16 MB
  float* cT     = (float*)take((size_t)B_*H_*4);
  float* W_dc   = (float*)take((size_t)G4_*H_*4);            // 1 MB
  float* Wc0    = (float*)take(G4_*4);
  float* Wc1    = (float*)take(G4_*4);
  float* bc     = (float*)take(G4_*4);
  float* b_dc   = (float*)take(G4_*4);
  float* WqT    = (float*)take((size_t)M_*H_*4);
  unsigned long long* ring_e = (unsigned long long*)take((size_t)NG_*RING_*1024*8); // 512 KB
  unsigned long long* ring_d = (unsigned long long*)take((size_t)NG_*RING_*1024*8); // 512 KB

  size_t used = (size_t)(p - (char*)d_ws);
  float* h_all;
  if (ws_size >= used + (size_t)T_*B_*H_*4) {
    h_all = (float*)take((size_t)T_*B_*H_*4);                // 64 MB
  } else {
    h_all = out;  // d_out is exactly T_*B_*H_ floats; dead before attn writes
  }

  // zero the tag rings (tags are 1..T so 0 never matches); re-zeroed every replay
  hipMemsetAsync(ring_e, 0, (size_t)NG_*RING_*1024*8, stream);
  hipMemsetAsync(ring_d, 0, (size_t)NG_*RING_*1024*8, stream);

  prep_all<<<1024 + 68, 256, 0, stream>>>(Wihd, Whhd, W_dc,
                                          Wp, bp, Wihe, bihe, bhhe, bihd, bhhd, Wq,
                                          Wc0, Wc1, bc, b_dc, WqT);
  enc_kernel<<<NG_*NSL_, 1024, 0, stream>>>(seq, slen, Whhe, Wc0, Wc1, bc,
                                            h_all, cT, ring_e);
  dec_kproj_kernel<<<NDEC_ + B_, 1024, 0, stream>>>(slen, W_dc, b_dc, h_all, cT,
                                                    h2_all, ring_d, Wk, bk, kproj);
  attn_kernel<<<B_*32, 256, 0, stream>>>(h2_all, kproj, WqT, bq, slen, out);
}